// Round 7
// baseline (507.424 us; speedup 1.0000x reference)
//
#include <hip/hip_runtime.h>
#include <math.h>

// Round 16: RESUBMISSION of round-15 (infra: "MI355X container failed twice",
// broker-outage signature — no pytest/profile output; content unindicted).
// Round-15 content, unchanged:
// (a) gemm201 cadence: stage 3 halves at P4/P8 (none at P1/P5), counted
//     vmcnt(8) AFTER the P4/P8 MFMA cluster. Raises the worst-half HBM cover
//     from 3 phases (~460cy) to 4+ (~620cy) and overlaps the drain with MFMA.
//     Race-audit: B(E+2) at P4 >= lastread(P3)+1; in-flight 8->10->16, oldest
//     8 = consumed tile at each wait; prologue tiles0+1 + vmcnt(8); peel vmcnt(0).
// (b) operand-swap epilogue (gemm201 + gemm_bt): mfma(BF,AF) makes each thread
//     hold 4 CONSECUTIVE columns (c=..+quad*4+i, r=..+l15) -> float4 bias/res
//     loads + single 8B(f16)/16B(f32) store per (mi,ni): 32 stores/thread vs 128.
// repack / LN / attention unchanged.

typedef _Float16 h16;
typedef __attribute__((ext_vector_type(8))) _Float16 f16x8;
typedef __attribute__((ext_vector_type(4))) float f32x4;

__device__ __forceinline__ void gl2lds16(const void* g, void* l) {
  __builtin_amdgcn_global_load_lds(
      (const __attribute__((address_space(1))) void*)g,
      (__attribute__((address_space(3))) void*)l, 16, 0, 0);
}

// ---------------- repack: tiled transpose fp32 -> f16 [N][K], + bias pack ----------
__global__ __launch_bounds__(256) void repack_kernel(
    const float* __restrict__ Wq, const float* __restrict__ Wk,
    const float* __restrict__ Wv, const float* __restrict__ Wo,
    const float* __restrict__ W1, const float* __restrict__ W2,
    const float* __restrict__ bq, const float* __restrict__ bk,
    const float* __restrict__ bv,
    h16* __restrict__ WqkvT, h16* __restrict__ WoT, h16* __restrict__ W1T,
    h16* __restrict__ W2T, float* __restrict__ bqkv)
{
  const int t = blockIdx.x;
  const int tid = threadIdx.x;
  if (t == 3072) {
    for (int i = tid; i < 3072; i += 256)
      bqkv[i] = (i < 1024) ? bq[i] : (i < 2048 ? bk[i - 1024] : bv[i - 2048]);
    return;
  }
  __shared__ float ld[64 * 65];

  const float* src; h16* dst;
  int sRS, dRS, k0, sn0, dn0;
  if (t < 768) {
    const int m = t >> 8, tt = t & 255, h = tt >> 4, tk = tt & 15;
    src = ((m == 0) ? Wq : (m == 1) ? Wk : Wv) + (size_t)h * 65536;
    dst = WqkvT; sRS = 64; dRS = 1024;
    k0 = tk * 64; sn0 = 0; dn0 = m * 1024 + h * 64;
  } else if (t < 1024) {
    const int tt = t - 768, tk = tt >> 4, tn = tt & 15;
    src = Wo; dst = WoT; sRS = 1024; dRS = 1024;
    k0 = tk * 64; sn0 = tn * 64; dn0 = tn * 64;
  } else if (t < 2048) {
    const int tt = t - 1024, tk = tt >> 6, tn = tt & 63;
    src = W1; dst = W1T; sRS = 4096; dRS = 1024;
    k0 = tk * 64; sn0 = tn * 64; dn0 = tn * 64;
  } else {
    const int tt = t - 2048, tk = tt >> 4, tn = tt & 15;
    src = W2; dst = W2T; sRS = 1024; dRS = 4096;
    k0 = tk * 64; sn0 = tn * 64; dn0 = tn * 64;
  }

  #pragma unroll
  for (int p = 0; p < 16; ++p) {
    const int idx = p * 256 + tid;
    const int r = idx >> 6, c = idx & 63;
    ld[c * 65 + r] = src[(size_t)(k0 + r) * sRS + sn0 + c];
  }
  __syncthreads();
  #pragma unroll
  for (int p = 0; p < 8; ++p) {
    const int idx = p * 512 + tid * 2;
    const int n = idx >> 6, k = idx & 63;
    union { unsigned int u; h16 e[2]; } pk;
    pk.e[0] = (h16)ld[n * 65 + k];
    pk.e[1] = (h16)ld[n * 65 + k + 1];
    *(unsigned int*)&dst[(size_t)(dn0 + n) * dRS + k0 + k] = pk.u;
  }
}

// ---------------- LayerNorm: (IT==0: fp32 in, IT==1: f16 in) -> f16 out ------------
template <int IT>
__global__ __launch_bounds__(256) void ln_kernel(
    const void* __restrict__ in, const float* __restrict__ gw,
    const float* __restrict__ bw, h16* __restrict__ outp)
{
  const int row = blockIdx.x;
  const int tid = threadIdx.x;
  float v[4];
  if (IT == 0) {
    const float* p = (const float*)in + (size_t)row * 1024 + tid * 4;
    float4 tt = *(const float4*)p;
    v[0] = tt.x; v[1] = tt.y; v[2] = tt.z; v[3] = tt.w;
  } else {
    const h16* p = (const h16*)in + (size_t)row * 1024 + tid * 4;
    union { uint2 u; h16 h[4]; } raw;
    raw.u = *(const uint2*)p;
    v[0] = (float)raw.h[0]; v[1] = (float)raw.h[1];
    v[2] = (float)raw.h[2]; v[3] = (float)raw.h[3];
  }
  float s = v[0] + v[1] + v[2] + v[3];
  float ss = v[0]*v[0] + v[1]*v[1] + v[2]*v[2] + v[3]*v[3];
  #pragma unroll
  for (int off = 32; off >= 1; off >>= 1) {
    s += __shfl_down(s, off);
    ss += __shfl_down(ss, off);
  }
  __shared__ float red[8];
  const int w = tid >> 6;
  if ((tid & 63) == 0) { red[w] = s; red[4 + w] = ss; }
  __syncthreads();
  s = red[0] + red[1] + red[2] + red[3];
  ss = red[4] + red[5] + red[6] + red[7];
  const float mean = s * (1.0f / 1024.0f);
  const float var = ss * (1.0f / 1024.0f) - mean * mean;
  const float inv = rsqrtf(fmaxf(var, 0.0f) + 1e-5f);
  union { uint2 u; h16 h[4]; } pk;
  #pragma unroll
  for (int i = 0; i < 4; ++i)
    pk.h[i] = (h16)((v[i] - mean) * inv * gw[tid * 4 + i] + bw[tid * 4 + i]);
  *(uint2*)(outp + (size_t)row * 1024 + tid * 4) = pk.u;
}

// ---- shared epilogue helper: thread holds C[r][c..c+3] (consecutive cols) ----
template <int MODE>
__device__ __forceinline__ void epi_store4(
    const f32x4& a, const float* __restrict__ bias, const void* __restrict__ res,
    void* __restrict__ out, size_t idx, int c)
{
  const float4 b4 = *(const float4*)&bias[c];
  float v0 = a[0] + b4.x, v1 = a[1] + b4.y, v2 = a[2] + b4.z, v3 = a[3] + b4.w;
  if (MODE == 1) {
    const float4 r4 = *(const float4*)&((const float*)res)[idx];
    v0 += r4.x; v1 += r4.y; v2 += r4.z; v3 += r4.w;
  } else if (MODE == 2) {
    const float e0 = __expf(v0 * (-1.5957691216f - 0.0713548163f * v0 * v0));
    const float e1 = __expf(v1 * (-1.5957691216f - 0.0713548163f * v1 * v1));
    const float e2 = __expf(v2 * (-1.5957691216f - 0.0713548163f * v2 * v2));
    const float e3 = __expf(v3 * (-1.5957691216f - 0.0713548163f * v3 * v3));
    v0 /= (1.0f + e0); v1 /= (1.0f + e1); v2 /= (1.0f + e2); v3 /= (1.0f + e3);
  } else if (MODE == 3) {
    union { uint2 u; h16 h[4]; } r4;
    r4.u = *(const uint2*)&((const h16*)res)[idx];
    v0 += (float)r4.h[0]; v1 += (float)r4.h[1];
    v2 += (float)r4.h[2]; v3 += (float)r4.h[3];
    float4 o4; o4.x = v0; o4.y = v1; o4.z = v2; o4.w = v3;
    *(float4*)&((float*)out)[idx] = o4;
    return;
  }
  union { uint2 u; h16 h[4]; } pk;
  pk.h[0] = (h16)v0; pk.h[1] = (h16)v1; pk.h[2] = (h16)v2; pk.h[3] = (h16)v3;
  *(uint2*)&((h16*)out)[idx] = pk.u;
}

// ================= gemm201: m201 8-phase, 256x256, BK=64, 2 tiles/iter =============
#define GEMM201_LDS 131072

template <int MODE>
__global__ __launch_bounds__(512, 2) void gemm201(
    const h16* __restrict__ A, const h16* __restrict__ BT,
    const float* __restrict__ bias, const void* __restrict__ res,
    void* __restrict__ out, int M, int N, int K)
{
  extern __shared__ __align__(16) char smem[];
  const int tid = threadIdx.x;
  const int lane = tid & 63, w = tid >> 6;
  const int l15 = lane & 15, quad = lane >> 4;
  const int wr = w >> 2, wc = w & 3;               // 2M x 4N waves, 128x64 each
  const int m0 = blockIdx.y * 256, n0 = blockIdx.x * 256;
  const int NI = K >> 7;                           // iterations (2 K-tiles each)

  // ---- staging: linear LDS dest (tid*16B), source pre-swizzled (rule #21) ----
  const int sr = tid >> 3;                         // row in 64-row chunk
  const int sk = ((tid & 7) ^ (sr & 7)) * 8;       // logical k-slot, h16 units
  const h16* gAs = A + (size_t)(m0 + sr) * K + sk;
  const h16* gBs = BT + (size_t)(n0 + sr) * K + sk;
  const int dst0 = tid * 16;

  // ---- fragment read addrs: phys slot = (ks*4+quad) ^ (row&7), row&7 == l15&7 ----
  const int x7 = l15 & 7;
  const int sw0 = (quad ^ x7) << 4;
  const int sw1 = ((4 + quad) ^ x7) << 4;
  const int aBase = wr * 16384;                    // + buf*65536
  const int bBase = 32768 + (wc >> 1) * 16384;
  const int bRow0 = (wc & 1) * 64;

  f32x4 zero = {0.f, 0.f, 0.f, 0.f};
  f32x4 acc[8][4];
  #pragma unroll
  for (int a = 0; a < 8; ++a)
    #pragma unroll
    for (int b = 0; b < 4; ++b) acc[a][b] = zero;

  f16x8 AF0[4][2], AF1[4][2], BF0[2][2], BF1[2][2];

  auto rdA = [&](int bufo, int mi0, f16x8 (&AF)[4][2]) {
    #pragma unroll
    for (int mi = 0; mi < 4; ++mi) {
      const char* p = smem + bufo + aBase + ((mi0 + mi) * 16 + l15) * 128;
      AF[mi][0] = *(const f16x8*)(p + sw0);
      AF[mi][1] = *(const f16x8*)(p + sw1);
    }
  };
  auto rdB = [&](int bufo, int ni0, f16x8 (&BF)[2][2]) {
    #pragma unroll
    for (int ni = 0; ni < 2; ++ni) {
      const char* p = smem + bufo + bBase + (bRow0 + (ni0 + ni) * 16 + l15) * 128;
      BF[ni][0] = *(const f16x8*)(p + sw0);
      BF[ni][1] = *(const f16x8*)(p + sw1);
    }
  };
  // operand-swapped: D rows <- B fragment (quad*4+i), D cols <- A fragment (l15).
  auto mmq = [&](int mi0, int ni0, f16x8 (&AF)[4][2], f16x8 (&BF)[2][2]) {
    __builtin_amdgcn_s_setprio(1);
    #pragma unroll
    for (int mi = 0; mi < 4; ++mi)
      #pragma unroll
      for (int ni = 0; ni < 2; ++ni) {
        acc[mi0 + mi][ni0 + ni] = __builtin_amdgcn_mfma_f32_16x16x32_f16(
            BF[ni][0], AF[mi][0], acc[mi0 + mi][ni0 + ni], 0, 0, 0);
        acc[mi0 + mi][ni0 + ni] = __builtin_amdgcn_mfma_f32_16x16x32_f16(
            BF[ni][1], AF[mi][1], acc[mi0 + mi][ni0 + ni], 0, 0, 0);
      }
    __builtin_amdgcn_s_setprio(0);
  };

#define STG_A(b, h, T) { \
    char* d_ = smem + (b) * 65536 + (h) * 16384 + dst0; \
    const h16* g_ = gAs + (size_t)((h) * 128) * K + (size_t)(T) * 64; \
    gl2lds16(g_, d_); gl2lds16(g_ + (size_t)64 * K, d_ + 8192); }
#define STG_B(b, h, T) { \
    char* d_ = smem + (b) * 65536 + 32768 + (h) * 16384 + dst0; \
    const h16* g_ = gBs + (size_t)((h) * 128) * K + (size_t)(T) * 64; \
    gl2lds16(g_, d_); gl2lds16(g_ + (size_t)64 * K, d_ + 8192); }
#define BAR __builtin_amdgcn_s_barrier()
#define VMC(n) { asm volatile("s_waitcnt vmcnt(" #n ")" ::: "memory"); \
                 __builtin_amdgcn_sched_barrier(0); }

  // ---- prologue: tile0 (4 halves) + tile1 (4 halves); vmcnt(8) keeps tile1 flying --
  STG_A(0, 0, 0); STG_A(0, 1, 0); STG_B(0, 0, 0); STG_B(0, 1, 0);
  STG_A(1, 0, 1); STG_A(1, 1, 1); STG_B(1, 0, 1); STG_B(1, 1, 1);
  VMC(8);                                          // tile0 resident; tile1 in flight
  BAR;

  for (int i = 0; i < NI - 1; ++i) {
    const int E = 2 * i, O = E + 1;
    // P1 (reads: A rows 0-63/128-191, B rows 0-31/64-95/128-159/192-223 of buf0)
    rdA(0, 0, AF0); rdB(0, 0, BF0);
    BAR; mmq(0, 0, AF0, BF0); BAR;
    // P2 (buf0 A last read)
    rdA(0, 4, AF1);
    BAR; mmq(4, 0, AF1, BF0); BAR;
    // P3 (buf0 B last read); stage Ah0(E+2)
    rdB(0, 2, BF1);
    STG_A(0, 0, E + 2);
    BAR; mmq(4, 2, AF1, BF1); BAR;
    // P4: stage Ah1+Bh0+Bh1(E+2); wait AFTER mmq (drain = tile O's 8 loads)
    STG_A(0, 1, E + 2); STG_B(0, 0, E + 2); STG_B(0, 1, E + 2);
    BAR; mmq(0, 2, AF0, BF1);
    VMC(8);
    BAR;
    // P5
    rdA(65536, 0, AF0); rdB(65536, 0, BF0);
    BAR; mmq(0, 0, AF0, BF0); BAR;
    // P6 (buf1 A last read)
    rdA(65536, 4, AF1);
    BAR; mmq(4, 0, AF1, BF0); BAR;
    // P7 (buf1 B last read); stage Ah0(O+2)
    rdB(65536, 2, BF1);
    STG_A(1, 0, O + 2);
    BAR; mmq(4, 2, AF1, BF1); BAR;
    // P8: stage Ah1+Bh0+Bh1(O+2); wait AFTER mmq (drain = tile E+2's 8 loads)
    STG_A(1, 1, O + 2); STG_B(1, 0, O + 2); STG_B(1, 1, O + 2);
    BAR; mmq(0, 2, AF0, BF1);
    VMC(8);
    BAR;
  }

  // ---- peeled final iteration: no staging; vmcnt(0) after P4's mmq ----
  {
    rdA(0, 0, AF0); rdB(0, 0, BF0);
    BAR; mmq(0, 0, AF0, BF0); BAR;
    rdA(0, 4, AF1);
    BAR; mmq(4, 0, AF1, BF0); BAR;
    rdB(0, 2, BF1);
    BAR; mmq(4, 2, AF1, BF1); BAR;
    BAR; mmq(0, 2, AF0, BF1);
    VMC(0);                                        // tile O fully resident
    BAR;
    rdA(65536, 0, AF0); rdB(65536, 0, BF0);
    BAR; mmq(0, 0, AF0, BF0); BAR;
    rdA(65536, 4, AF1);
    BAR; mmq(4, 0, AF1, BF0); BAR;
    rdB(65536, 2, BF1);
    BAR; mmq(4, 2, AF1, BF1); BAR;
    mmq(0, 2, AF0, BF1);
  }

  // ---- epilogue: r = ..+l15, c = ..+quad*4 (+i) — vectorized 4-wide ----
  #pragma unroll
  for (int mi = 0; mi < 8; ++mi) {
    const int r = m0 + wr * 128 + mi * 16 + l15;
    #pragma unroll
    for (int ni = 0; ni < 4; ++ni) {
      const int c = n0 + wc * 64 + ni * 16 + quad * 4;
      epi_store4<MODE>(acc[mi][ni], bias, res, out, (size_t)r * N + c, c);
    }
  }
#undef STG_A
#undef STG_B
#undef BAR
#undef VMC
}

// ---------------- GEMM (round-10): 256x128 tile, kept for N=1024 GEMMs -------------
#define GEMM_LDS 147456

template <int MODE>
__global__ __launch_bounds__(512, 2) void gemm_bt(
    const h16* __restrict__ A, const h16* __restrict__ BT,
    const float* __restrict__ bias, const void* __restrict__ res,
    void* __restrict__ out, int M, int N, int K)
{
  extern __shared__ __align__(16) char smem[];
  const int tid = threadIdx.x;
  const int lane = tid & 63, w = tid >> 6;
  const int l15 = lane & 15, quad = lane >> 4;
  const int wm = w >> 1, wn = w & 1;
  const int m0 = blockIdx.y * 256, n0 = blockIdx.x * 128;
  const int NT = K >> 6;

  const int srow = w * 8 + (lane >> 3);
  const int scol = ((lane & 7) ^ ((lane >> 3) & 7)) * 8;
  const h16* gA = A + (size_t)(m0 + srow) * K + scol;
  const h16* gB = BT + (size_t)(n0 + srow) * K + scol;
  const int ldsw = w * 1024;

  const int arow = wm * 64 + l15;
  const int brow = wn * 64 + l15;
  const int x7 = l15 & 7;
  const int sw0 = (quad ^ x7) << 4;
  const int sw1 = ((4 | quad) ^ x7) << 4;

  f32x4 zero = {0.f, 0.f, 0.f, 0.f};
  f32x4 acc[4][4];
  #pragma unroll
  for (int a = 0; a < 4; ++a)
    #pragma unroll
    for (int b = 0; b < 4; ++b) acc[a][b] = zero;

  {
    char* b0 = smem;
    char* b1 = smem + 49152;
    #pragma unroll
    for (int j = 0; j < 4; ++j) gl2lds16(gA + (size_t)j * 64 * K, b0 + j * 8192 + ldsw);
    #pragma unroll
    for (int j = 0; j < 2; ++j) gl2lds16(gB + (size_t)j * 64 * K, b0 + 32768 + j * 8192 + ldsw);
    #pragma unroll
    for (int j = 0; j < 4; ++j) gl2lds16(gA + 64 + (size_t)j * 64 * K, b1 + j * 8192 + ldsw);
    #pragma unroll
    for (int j = 0; j < 2; ++j) gl2lds16(gB + 64 + (size_t)j * 64 * K, b1 + 32768 + j * 8192 + ldsw);
  }
  asm volatile("s_waitcnt vmcnt(6)" ::: "memory");
  __builtin_amdgcn_sched_barrier(0);
  __builtin_amdgcn_s_barrier();

  int cur = 0, pre = 2;
  for (int t = 0; t < NT; ++t) {
    const char* Ab = smem + cur * 49152;
    const char* Bb = Ab + 32768;
    char* Pb = smem + pre * 49152;
    const bool pf = (t + 2) < NT;
    f16x8 af[4], af1[4], bf[4][2];

    #pragma unroll
    for (int mi = 0; mi < 4; ++mi)
      af[mi] = *(const f16x8*)(Ab + (arow + mi * 16) * 128 + sw0);
    #pragma unroll
    for (int mi = 0; mi < 4; ++mi)
      af1[mi] = *(const f16x8*)(Ab + (arow + mi * 16) * 128 + sw1);
    #pragma unroll
    for (int ni = 0; ni < 2; ++ni) {
      bf[ni][0] = *(const f16x8*)(Bb + (brow + ni * 16) * 128 + sw0);
      bf[ni][1] = *(const f16x8*)(Bb + (brow + ni * 16) * 128 + sw1);
    }
    if (pf) {
      const h16* g = gA + (size_t)(t + 2) * 64;
      #pragma unroll
      for (int j = 0; j < 4; ++j) gl2lds16(g + (size_t)j * 64 * K, Pb + j * 8192 + ldsw);
    }
    __builtin_amdgcn_s_barrier();
    __builtin_amdgcn_s_setprio(1);
    #pragma unroll
    for (int mi = 0; mi < 4; ++mi)
      #pragma unroll
      for (int ni = 0; ni < 2; ++ni) {
        acc[mi][ni] = __builtin_amdgcn_mfma_f32_16x16x32_f16(bf[ni][0], af[mi], acc[mi][ni], 0, 0, 0);
        acc[mi][ni] = __builtin_amdgcn_mfma_f32_16x16x32_f16(bf[ni][1], af1[mi], acc[mi][ni], 0, 0, 0);
      }
    __builtin_amdgcn_s_setprio(0);
    __builtin_amdgcn_s_barrier();

    #pragma unroll
    for (int ni = 2; ni < 4; ++ni) {
      bf[ni][0] = *(const f16x8*)(Bb + (brow + ni * 16) * 128 + sw0);
      bf[ni][1] = *(const f16x8*)(Bb + (brow + ni * 16) * 128 + sw1);
    }
    if (pf) {
      const h16* g = gB + (size_t)(t + 2) * 64;
      #pragma unroll
      for (int j = 0; j < 2; ++j) gl2lds16(g + (size_t)j * 64 * K, Pb + 32768 + j * 8192 + ldsw);
    }
    __builtin_amdgcn_s_barrier();
    __builtin_amdgcn_s_setprio(1);
    #pragma unroll
    for (int mi = 0; mi < 4; ++mi)
      #pragma unroll
      for (int ni = 2; ni < 4; ++ni) {
        acc[mi][ni] = __builtin_amdgcn_mfma_f32_16x16x32_f16(bf[ni][0], af[mi], acc[mi][ni], 0, 0, 0);
        acc[mi][ni] = __builtin_amdgcn_mfma_f32_16x16x32_f16(bf[ni][1], af1[mi], acc[mi][ni], 0, 0, 0);
      }
    __builtin_amdgcn_s_setprio(0);
    if (pf) {
      asm volatile("s_waitcnt vmcnt(6)" ::: "memory");
    } else if (t + 2 == NT) {
      asm volatile("s_waitcnt vmcnt(0)" ::: "memory");
    }
    __builtin_amdgcn_sched_barrier(0);
    __builtin_amdgcn_s_barrier();
    cur = (cur == 2) ? 0 : cur + 1;
    pre = (pre == 2) ? 0 : pre + 1;
  }

  #pragma unroll
  for (int mi = 0; mi < 4; ++mi) {
    const int r = m0 + wm * 64 + mi * 16 + l15;
    #pragma unroll
    for (int ni = 0; ni < 4; ++ni) {
      const int c = n0 + wn * 64 + ni * 16 + quad * 4;
      epi_store4<MODE>(acc[mi][ni], bias, res, out, (size_t)r * N + c, c);
    }
  }
}

// ---------------- Flash attention (no-max softmax): qkv f16 -> ctx f16 --------------
__global__ __launch_bounds__(256, 2) void attn_kernel(
    const h16* __restrict__ qkv, h16* __restrict__ ctx)
{
  const int qb = blockIdx.x;
  const int bh = blockIdx.y;
  const int b = bh >> 4, h = bh & 15;
  const int tid = threadIdx.x;
  const int w = tid >> 6, lane = tid & 63;
  const int l15 = lane & 15, quad = lane >> 4;

  __shared__ __align__(16) h16 Ks[64 * 80];
  __shared__ __align__(16) h16 Vt[64 * 80];
  __shared__ __align__(16) h16 Ps[256 * 80];

  const size_t qrow0 = (size_t)(b * 1024 + qb * 256);
  for (int c = tid; c < 2048; c += 256) {
    const int row = c >> 3, kc = (c & 7) * 8;
    uint4 raw = *(const uint4*)(qkv + (qrow0 + row) * 3072 + h * 64 + kc);
    union { uint4 v; h16 e[8]; } in4, out4;
    in4.v = raw;
    #pragma unroll
    for (int i = 0; i < 8; ++i) out4.e[i] = in4.e[i] * (h16)0.125f;
    *(uint4*)&Ps[row * 80 + kc] = out4.v;
  }
  __syncthreads();
  f16x8 aq[4][2];
  #pragma unroll
  for (int r = 0; r < 4; ++r)
    #pragma unroll
    for (int s = 0; s < 2; ++s)
      aq[r][s] = *(const f16x8*)&Ps[(w * 64 + r * 16 + l15) * 80 + s * 32 + quad * 8];

  f32x4 zero = {0.f, 0.f, 0.f, 0.f};
  f32x4 o_acc[4][4];
  float l_p[4][4];
  #pragma unroll
  for (int r = 0; r < 4; ++r)
    #pragma unroll
    for (int i = 0; i < 4; ++i) { o_acc[r][i] = zero; l_p[r][i] = 0.f; }

  h16* Pw = &Ps[w * 64 * 80];

  for (int jt = 0; jt < 16; ++jt) {
    __syncthreads();
    const size_t kv0 = (size_t)(b * 1024 + jt * 64);
    for (int c = tid; c < 512; c += 256) {
      const int row = c >> 3, kc = (c & 7) * 8;
      *(uint4*)&Ks[row * 80 + kc] =
          *(const uint4*)(qkv + (kv0 + row) * 3072 + 1024 + h * 64 + kc);
    }
    #pragma unroll
    for (int cc = 0; cc < 2; ++cc) {
      const int d0 = (w + cc * 4) * 8;
      uint4 raw = *(const uint4*)(qkv + (kv0 + lane) * 3072 + 2048 + h * 64 + d0);
      union { uint4 v; h16 e[8]; } in4;
      in4.v = raw;
      #pragma unroll
      for (int i = 0; i < 8; ++i) Vt[(d0 + i) * 80 + lane] = in4.e[i];
    }
    __syncthreads();

    f16x8 kf[4][2];
    #pragma unroll
    for (int ni = 0; ni < 4; ++ni)
      #pragma unroll
      for (int s = 0; s < 2; ++s)
        kf[ni][s] = *(const f16x8*)&Ks[(ni * 16 + l15) * 80 + s * 32 + quad * 8];
    #pragma unroll
    for (int r = 0; r < 4; ++r) {
      f32x4 s_acc[4];
      #pragma unroll
      for (int i = 0; i < 4; ++i) s_acc[i] = zero;
      #pragma unroll
      for (int ni = 0; ni < 4; ++ni)
        #pragma unroll
        for (int s = 0; s < 2; ++s)
          s_acc[ni] = __builtin_amdgcn_mfma_f32_16x16x32_f16(aq[r][s], kf[ni][s], s_acc[ni], 0, 0, 0);
      #pragma unroll
      for (int ni = 0; ni < 4; ++ni)
        #pragma unroll
        for (int i = 0; i < 4; ++i) {
          float p = __expf(s_acc[ni][i]);
          l_p[r][i] += p;
          Pw[(r * 16 + quad * 4 + i) * 80 + ni * 16 + l15] = (h16)p;
        }
    }

    f16x8 vf[4][2];
    #pragma unroll
    for (int ni = 0; ni < 4; ++ni)
      #pragma unroll
      for (int s = 0; s < 2; ++s)
        vf[ni][s] = *(const f16x8*)&Vt[(ni * 16 + l15) * 80 + s * 32 + quad * 8];
    #pragma unroll
    for (int r = 0; r < 4; ++r) {
      f16x8 ap0 = *(const f16x8*)&Pw[(r * 16 + l15) * 80 + quad * 8];
      f16x8 ap1 = *(const f16x8*)&Pw[(r * 16 + l15) * 80 + 32 + quad * 8];
      #pragma unroll
      for (int ni = 0; ni < 4; ++ni) {
        o_acc[r][ni] = __builtin_amdgcn_mfma_f32_16x16x32_f16(ap0, vf[ni][0], o_acc[r][ni], 0, 0, 0);
        o_acc[r][ni] = __builtin_amdgcn_mfma_f32_16x16x32_f16(ap1, vf[ni][1], o_acc[r][ni], 0, 0, 0);
      }
    }
  }

  #pragma unroll
  for (int r = 0; r < 4; ++r)
    #pragma unroll
    for (int i = 0; i < 4; ++i) {
      float lt = l_p[r][i];
      #pragma unroll
      for (int off = 1; off < 16; off <<= 1) lt += __shfl_xor(lt, off);
      const float rinv = 1.0f / lt;
      const size_t row = qrow0 + w * 64 + r * 16 + quad * 4 + i;
      #pragma unroll
      for (int ni = 0; ni < 4; ++ni)
        ctx[row * 1024 + h * 64 + ni * 16 + l15] = (h16)(o_acc[r][ni][i] * rinv);
    }
}

// ---------------- launcher ----------------
extern "C" void kernel_launch(void* const* d_in, const int* in_sizes, int n_in,
                              void* d_out, int out_size, void* d_ws, size_t ws_size,
                              hipStream_t stream) {
  const float* x   = (const float*)d_in[0];
  const float* Wq  = (const float*)d_in[1];
  const float* bq  = (const float*)d_in[2];
  const float* Wk  = (const float*)d_in[3];
  const float* bk  = (const float*)d_in[4];
  const float* Wv  = (const float*)d_in[5];
  const float* bv  = (const float*)d_in[6];
  const float* Wo  = (const float*)d_in[7];
  const float* bo  = (const float*)d_in[8];
  const float* g1  = (const float*)d_in[9];
  const float* be1 = (const float*)d_in[10];
  const float* g2  = (const float*)d_in[11];
  const float* be2 = (const float*)d_in[12];
  const float* W1  = (const float*)d_in[13];
  const float* c1  = (const float*)d_in[14];
  const float* W2  = (const float*)d_in[15];
  const float* c2  = (const float*)d_in[16];

  char* ws = (char*)d_ws;
  h16*   WqkvT = (h16*)(ws + 0);
  h16*   WoT   = (h16*)(ws + 6291456);
  h16*   W1T   = (h16*)(ws + 8388608);
  h16*   W2T   = (h16*)(ws + 16777216);
  float* bqkv  = (float*)(ws + 25165824);
  h16*   bufA  = (h16*)(ws + 25178112);    // xn1 / ctx / xn2
  h16*   qkv   = (h16*)(ws + 41955328);
  h16*   x1    = (h16*)(ws + 41955328);    // aliases dead qkv
  h16*   hbuf  = (h16*)(ws + 58732544);

  static bool attr_done = false;
  if (!attr_done) {
    hipFuncSetAttribute((const void*)gemm_bt<1>, hipFuncAttributeMaxDynamicSharedMemorySize, GEMM_LDS);
    hipFuncSetAttribute((const void*)gemm_bt<3>, hipFuncAttributeMaxDynamicSharedMemorySize, GEMM_LDS);
    hipFuncSetAttribute((const void*)gemm201<0>, hipFuncAttributeMaxDynamicSharedMemorySize, GEMM201_LDS);
    hipFuncSetAttribute((const void*)gemm201<2>, hipFuncAttributeMaxDynamicSharedMemorySize, GEMM201_LDS);
    attr_done = true;
  }

  repack_kernel<<<dim3(3073), dim3(256), 0, stream>>>(Wq, Wk, Wv, Wo, W1, W2, bq, bk, bv,
                                                      WqkvT, WoT, W1T, W2T, bqkv);
  ln_kernel<0><<<dim3(8192), dim3(256), 0, stream>>>(x, g1, be1, bufA);        // xn1
  gemm201<0><<<dim3(12, 32), dim3(512), GEMM201_LDS, stream>>>(bufA, WqkvT, bqkv, nullptr, qkv,
                                                               8192, 3072, 1024);
  attn_kernel<<<dim3(4, 128), dim3(256), 0, stream>>>(qkv, bufA);              // ctx
  gemm_bt<1><<<dim3(8, 32), dim3(512), GEMM_LDS, stream>>>(bufA, WoT, bo, x, x1,
                                                           8192, 1024, 1024);
  ln_kernel<1><<<dim3(8192), dim3(256), 0, stream>>>(x1, g2, be2, bufA);       // xn2
  gemm201<2><<<dim3(16, 32), dim3(512), GEMM201_LDS, stream>>>(bufA, W1T, c1, nullptr, hbuf,
                                                               8192, 4096, 1024);
  gemm_bt<3><<<dim3(8, 32), dim3(512), GEMM_LDS, stream>>>(hbuf, W2T, c2, x1, d_out,
                                                           8192, 1024, 4096);
}

// Round 8
// 499.194 us; speedup vs baseline: 1.0165x; 1.0165x over previous
//
#include <hip/hip_runtime.h>
#include <math.h>

// Round 17: unbundle the r15 regression. Base = r14 gemm201 cadence (verified
// 482.9us) with ONLY change (b) applied (proven correct in r7's bench):
//  - mmq computes mfma(BF, AF): thread holds 4 CONSECUTIVE output columns
//    (c = ..+quad*4+i, r = ..+l15) -> float4 bias/res loads + one 8B(f16)/
//    16B(fp32) store per (mi,ni). 32 stores/thread instead of 128.
//  - r15's cadence shift (cluster stage at P4/P8, vmcnt after mmq) REVERTED:
//    r7 counters showed it cost ~4us on MLP1 (VMEM burst backs up the queue).
// gemm201 cadence (= r14): P1:Bh1(O) P3:Ah0(E+2) P4:Ah1+Bh0(E+2)+vm6
//                          P5:Bh1(E+2) P7:Ah0(O+2) P8:Ah1+Bh0(O+2)+vm6
// repack / LN / attention unchanged.

typedef _Float16 h16;
typedef __attribute__((ext_vector_type(8))) _Float16 f16x8;
typedef __attribute__((ext_vector_type(4))) float f32x4;

__device__ __forceinline__ void gl2lds16(const void* g, void* l) {
  __builtin_amdgcn_global_load_lds(
      (const __attribute__((address_space(1))) void*)g,
      (__attribute__((address_space(3))) void*)l, 16, 0, 0);
}

// ---------------- repack: tiled transpose fp32 -> f16 [N][K], + bias pack ----------
__global__ __launch_bounds__(256) void repack_kernel(
    const float* __restrict__ Wq, const float* __restrict__ Wk,
    const float* __restrict__ Wv, const float* __restrict__ Wo,
    const float* __restrict__ W1, const float* __restrict__ W2,
    const float* __restrict__ bq, const float* __restrict__ bk,
    const float* __restrict__ bv,
    h16* __restrict__ WqkvT, h16* __restrict__ WoT, h16* __restrict__ W1T,
    h16* __restrict__ W2T, float* __restrict__ bqkv)
{
  const int t = blockIdx.x;
  const int tid = threadIdx.x;
  if (t == 3072) {
    for (int i = tid; i < 3072; i += 256)
      bqkv[i] = (i < 1024) ? bq[i] : (i < 2048 ? bk[i - 1024] : bv[i - 2048]);
    return;
  }
  __shared__ float ld[64 * 65];

  const float* src; h16* dst;
  int sRS, dRS, k0, sn0, dn0;
  if (t < 768) {
    const int m = t >> 8, tt = t & 255, h = tt >> 4, tk = tt & 15;
    src = ((m == 0) ? Wq : (m == 1) ? Wk : Wv) + (size_t)h * 65536;
    dst = WqkvT; sRS = 64; dRS = 1024;
    k0 = tk * 64; sn0 = 0; dn0 = m * 1024 + h * 64;
  } else if (t < 1024) {
    const int tt = t - 768, tk = tt >> 4, tn = tt & 15;
    src = Wo; dst = WoT; sRS = 1024; dRS = 1024;
    k0 = tk * 64; sn0 = tn * 64; dn0 = tn * 64;
  } else if (t < 2048) {
    const int tt = t - 1024, tk = tt >> 6, tn = tt & 63;
    src = W1; dst = W1T; sRS = 4096; dRS = 1024;
    k0 = tk * 64; sn0 = tn * 64; dn0 = tn * 64;
  } else {
    const int tt = t - 2048, tk = tt >> 4, tn = tt & 15;
    src = W2; dst = W2T; sRS = 1024; dRS = 4096;
    k0 = tk * 64; sn0 = tn * 64; dn0 = tn * 64;
  }

  #pragma unroll
  for (int p = 0; p < 16; ++p) {
    const int idx = p * 256 + tid;
    const int r = idx >> 6, c = idx & 63;
    ld[c * 65 + r] = src[(size_t)(k0 + r) * sRS + sn0 + c];
  }
  __syncthreads();
  #pragma unroll
  for (int p = 0; p < 8; ++p) {
    const int idx = p * 512 + tid * 2;
    const int n = idx >> 6, k = idx & 63;
    union { unsigned int u; h16 e[2]; } pk;
    pk.e[0] = (h16)ld[n * 65 + k];
    pk.e[1] = (h16)ld[n * 65 + k + 1];
    *(unsigned int*)&dst[(size_t)(dn0 + n) * dRS + k0 + k] = pk.u;
  }
}

// ---------------- LayerNorm: (IT==0: fp32 in, IT==1: f16 in) -> f16 out ------------
template <int IT>
__global__ __launch_bounds__(256) void ln_kernel(
    const void* __restrict__ in, const float* __restrict__ gw,
    const float* __restrict__ bw, h16* __restrict__ outp)
{
  const int row = blockIdx.x;
  const int tid = threadIdx.x;
  float v[4];
  if (IT == 0) {
    const float* p = (const float*)in + (size_t)row * 1024 + tid * 4;
    float4 tt = *(const float4*)p;
    v[0] = tt.x; v[1] = tt.y; v[2] = tt.z; v[3] = tt.w;
  } else {
    const h16* p = (const h16*)in + (size_t)row * 1024 + tid * 4;
    union { uint2 u; h16 h[4]; } raw;
    raw.u = *(const uint2*)p;
    v[0] = (float)raw.h[0]; v[1] = (float)raw.h[1];
    v[2] = (float)raw.h[2]; v[3] = (float)raw.h[3];
  }
  float s = v[0] + v[1] + v[2] + v[3];
  float ss = v[0]*v[0] + v[1]*v[1] + v[2]*v[2] + v[3]*v[3];
  #pragma unroll
  for (int off = 32; off >= 1; off >>= 1) {
    s += __shfl_down(s, off);
    ss += __shfl_down(ss, off);
  }
  __shared__ float red[8];
  const int w = tid >> 6;
  if ((tid & 63) == 0) { red[w] = s; red[4 + w] = ss; }
  __syncthreads();
  s = red[0] + red[1] + red[2] + red[3];
  ss = red[4] + red[5] + red[6] + red[7];
  const float mean = s * (1.0f / 1024.0f);
  const float var = ss * (1.0f / 1024.0f) - mean * mean;
  const float inv = rsqrtf(fmaxf(var, 0.0f) + 1e-5f);
  union { uint2 u; h16 h[4]; } pk;
  #pragma unroll
  for (int i = 0; i < 4; ++i)
    pk.h[i] = (h16)((v[i] - mean) * inv * gw[tid * 4 + i] + bw[tid * 4 + i]);
  *(uint2*)(outp + (size_t)row * 1024 + tid * 4) = pk.u;
}

// ---- shared epilogue helper: thread holds C[r][c..c+3] (consecutive cols) ----
template <int MODE>
__device__ __forceinline__ void epi_store4(
    const f32x4& a, const float* __restrict__ bias, const void* __restrict__ res,
    void* __restrict__ out, size_t idx, int c)
{
  const float4 b4 = *(const float4*)&bias[c];
  float v0 = a[0] + b4.x, v1 = a[1] + b4.y, v2 = a[2] + b4.z, v3 = a[3] + b4.w;
  if (MODE == 1) {
    const float4 r4 = *(const float4*)&((const float*)res)[idx];
    v0 += r4.x; v1 += r4.y; v2 += r4.z; v3 += r4.w;
  } else if (MODE == 2) {
    const float e0 = __expf(v0 * (-1.5957691216f - 0.0713548163f * v0 * v0));
    const float e1 = __expf(v1 * (-1.5957691216f - 0.0713548163f * v1 * v1));
    const float e2 = __expf(v2 * (-1.5957691216f - 0.0713548163f * v2 * v2));
    const float e3 = __expf(v3 * (-1.5957691216f - 0.0713548163f * v3 * v3));
    v0 /= (1.0f + e0); v1 /= (1.0f + e1); v2 /= (1.0f + e2); v3 /= (1.0f + e3);
  } else if (MODE == 3) {
    union { uint2 u; h16 h[4]; } r4;
    r4.u = *(const uint2*)&((const h16*)res)[idx];
    v0 += (float)r4.h[0]; v1 += (float)r4.h[1];
    v2 += (float)r4.h[2]; v3 += (float)r4.h[3];
    float4 o4; o4.x = v0; o4.y = v1; o4.z = v2; o4.w = v3;
    *(float4*)&((float*)out)[idx] = o4;
    return;
  }
  union { uint2 u; h16 h[4]; } pk;
  pk.h[0] = (h16)v0; pk.h[1] = (h16)v1; pk.h[2] = (h16)v2; pk.h[3] = (h16)v3;
  *(uint2*)&((h16*)out)[idx] = pk.u;
}

// ================= gemm201: m201 8-phase, 256x256, BK=64, 2 tiles/iter =============
#define GEMM201_LDS 131072

template <int MODE>
__global__ __launch_bounds__(512, 2) void gemm201(
    const h16* __restrict__ A, const h16* __restrict__ BT,
    const float* __restrict__ bias, const void* __restrict__ res,
    void* __restrict__ out, int M, int N, int K)
{
  extern __shared__ __align__(16) char smem[];
  const int tid = threadIdx.x;
  const int lane = tid & 63, w = tid >> 6;
  const int l15 = lane & 15, quad = lane >> 4;
  const int wr = w >> 2, wc = w & 3;               // 2M x 4N waves, 128x64 each
  const int m0 = blockIdx.y * 256, n0 = blockIdx.x * 256;
  const int NI = K >> 7;                           // iterations (2 K-tiles each)

  // ---- staging: linear LDS dest (tid*16B), source pre-swizzled (rule #21) ----
  const int sr = tid >> 3;                         // row in 64-row chunk
  const int sk = ((tid & 7) ^ (sr & 7)) * 8;       // logical k-slot, h16 units
  const h16* gAs = A + (size_t)(m0 + sr) * K + sk;
  const h16* gBs = BT + (size_t)(n0 + sr) * K + sk;
  const int dst0 = tid * 16;

  // ---- fragment read addrs: phys slot = (ks*4+quad) ^ (row&7), row&7 == l15&7 ----
  const int x7 = l15 & 7;
  const int sw0 = (quad ^ x7) << 4;
  const int sw1 = ((4 + quad) ^ x7) << 4;
  const int aBase = wr * 16384;                    // + buf*65536
  const int bBase = 32768 + (wc >> 1) * 16384;
  const int bRow0 = (wc & 1) * 64;

  f32x4 zero = {0.f, 0.f, 0.f, 0.f};
  f32x4 acc[8][4];
  #pragma unroll
  for (int a = 0; a < 8; ++a)
    #pragma unroll
    for (int b = 0; b < 4; ++b) acc[a][b] = zero;

  f16x8 AF0[4][2], AF1[4][2], BF0[2][2], BF1[2][2];

  auto rdA = [&](int bufo, int mi0, f16x8 (&AF)[4][2]) {
    #pragma unroll
    for (int mi = 0; mi < 4; ++mi) {
      const char* p = smem + bufo + aBase + ((mi0 + mi) * 16 + l15) * 128;
      AF[mi][0] = *(const f16x8*)(p + sw0);
      AF[mi][1] = *(const f16x8*)(p + sw1);
    }
  };
  auto rdB = [&](int bufo, int ni0, f16x8 (&BF)[2][2]) {
    #pragma unroll
    for (int ni = 0; ni < 2; ++ni) {
      const char* p = smem + bufo + bBase + (bRow0 + (ni0 + ni) * 16 + l15) * 128;
      BF[ni][0] = *(const f16x8*)(p + sw0);
      BF[ni][1] = *(const f16x8*)(p + sw1);
    }
  };
  // operand-swapped: D rows(reg) <- BF's 16-dim (n), D cols(l15) <- AF's 16-dim (m).
  auto mmq = [&](int mi0, int ni0, f16x8 (&AF)[4][2], f16x8 (&BF)[2][2]) {
    __builtin_amdgcn_s_setprio(1);
    #pragma unroll
    for (int mi = 0; mi < 4; ++mi)
      #pragma unroll
      for (int ni = 0; ni < 2; ++ni) {
        acc[mi0 + mi][ni0 + ni] = __builtin_amdgcn_mfma_f32_16x16x32_f16(
            BF[ni][0], AF[mi][0], acc[mi0 + mi][ni0 + ni], 0, 0, 0);
        acc[mi0 + mi][ni0 + ni] = __builtin_amdgcn_mfma_f32_16x16x32_f16(
            BF[ni][1], AF[mi][1], acc[mi0 + mi][ni0 + ni], 0, 0, 0);
      }
    __builtin_amdgcn_s_setprio(0);
  };

#define STG_A(b, h, T) { \
    char* d_ = smem + (b) * 65536 + (h) * 16384 + dst0; \
    const h16* g_ = gAs + (size_t)((h) * 128) * K + (size_t)(T) * 64; \
    gl2lds16(g_, d_); gl2lds16(g_ + (size_t)64 * K, d_ + 8192); }
#define STG_B(b, h, T) { \
    char* d_ = smem + (b) * 65536 + 32768 + (h) * 16384 + dst0; \
    const h16* g_ = gBs + (size_t)((h) * 128) * K + (size_t)(T) * 64; \
    gl2lds16(g_, d_); gl2lds16(g_ + (size_t)64 * K, d_ + 8192); }
#define BAR __builtin_amdgcn_s_barrier()
#define VMC(n) { asm volatile("s_waitcnt vmcnt(" #n ")" ::: "memory"); \
                 __builtin_amdgcn_sched_barrier(0); }

  // ---- prologue: tile0 (4 halves) + tile1 {Ah0, Ah1, Bh0} ----
  STG_A(0, 0, 0); STG_A(0, 1, 0); STG_B(0, 0, 0); STG_B(0, 1, 0);
  STG_A(1, 0, 1); STG_A(1, 1, 1); STG_B(1, 0, 1);
  VMC(6);                                          // tile0 landed; 3 halves fly
  BAR;

  for (int i = 0; i < NI - 1; ++i) {
    const int E = 2 * i, O = E + 1;
    // P1
    rdA(0, 0, AF0); rdB(0, 0, BF0);
    STG_B(1, 1, O);
    BAR; mmq(0, 0, AF0, BF0); BAR;
    // P2 (buf0 A last read)
    rdA(0, 4, AF1);
    BAR; mmq(4, 0, AF1, BF0); BAR;
    // P3 (buf0 B last read); stage Ah0(E+2)
    rdB(0, 2, BF1);
    STG_A(0, 0, E + 2);
    BAR; mmq(4, 2, AF1, BF1); BAR;
    // P4 (pure compute): stage remaining buf0 A+B halves, then counted wait
    STG_A(0, 1, E + 2); STG_B(0, 0, E + 2);
    VMC(6);                                        // tile O fully resident
    BAR; mmq(0, 2, AF0, BF1); BAR;
    // P5
    rdA(65536, 0, AF0); rdB(65536, 0, BF0);
    STG_B(0, 1, E + 2);
    BAR; mmq(0, 0, AF0, BF0); BAR;
    // P6 (buf1 A last read)
    rdA(65536, 4, AF1);
    BAR; mmq(4, 0, AF1, BF0); BAR;
    // P7 (buf1 B last read); stage Ah0(O+2)
    rdB(65536, 2, BF1);
    STG_A(1, 0, O + 2);
    BAR; mmq(4, 2, AF1, BF1); BAR;
    // P8 (pure compute)
    STG_A(1, 1, O + 2); STG_B(1, 0, O + 2);
    VMC(6);                                        // tile E+2 fully resident
    BAR; mmq(0, 2, AF0, BF1); BAR;
  }

  // ---- peeled final iteration (E = 2NI-2, O = 2NI-1): only Bh1(O) staged ----
  {
    const int O = 2 * NI - 1;
    rdA(0, 0, AF0); rdB(0, 0, BF0);
    STG_B(1, 1, O);
    BAR; mmq(0, 0, AF0, BF0); BAR;
    rdA(0, 4, AF1);
    BAR; mmq(4, 0, AF1, BF0); BAR;
    rdB(0, 2, BF1);
    BAR; mmq(4, 2, AF1, BF1); BAR;
    VMC(0);                                        // tile O fully resident
    BAR; mmq(0, 2, AF0, BF1); BAR;
    rdA(65536, 0, AF0); rdB(65536, 0, BF0);
    BAR; mmq(0, 0, AF0, BF0); BAR;
    rdA(65536, 4, AF1);
    BAR; mmq(4, 0, AF1, BF0); BAR;
    rdB(65536, 2, BF1);
    BAR; mmq(4, 2, AF1, BF1); BAR;
    mmq(0, 2, AF0, BF1);
  }

  // ---- epilogue: r = ..+l15, c = ..+quad*4 (+i) — vectorized 4-wide ----
  #pragma unroll
  for (int mi = 0; mi < 8; ++mi) {
    const int r = m0 + wr * 128 + mi * 16 + l15;
    #pragma unroll
    for (int ni = 0; ni < 4; ++ni) {
      const int c = n0 + wc * 64 + ni * 16 + quad * 4;
      epi_store4<MODE>(acc[mi][ni], bias, res, out, (size_t)r * N + c, c);
    }
  }
#undef STG_A
#undef STG_B
#undef BAR
#undef VMC
}

// ---------------- GEMM (round-10): 256x128 tile, kept for N=1024 GEMMs -------------
#define GEMM_LDS 147456

template <int MODE>
__global__ __launch_bounds__(512, 2) void gemm_bt(
    const h16* __restrict__ A, const h16* __restrict__ BT,
    const float* __restrict__ bias, const void* __restrict__ res,
    void* __restrict__ out, int M, int N, int K)
{
  extern __shared__ __align__(16) char smem[];
  const int tid = threadIdx.x;
  const int lane = tid & 63, w = tid >> 6;
  const int l15 = lane & 15, quad = lane >> 4;
  const int wm = w >> 1, wn = w & 1;
  const int m0 = blockIdx.y * 256, n0 = blockIdx.x * 128;
  const int NT = K >> 6;

  const int srow = w * 8 + (lane >> 3);
  const int scol = ((lane & 7) ^ ((lane >> 3) & 7)) * 8;
  const h16* gA = A + (size_t)(m0 + srow) * K + scol;
  const h16* gB = BT + (size_t)(n0 + srow) * K + scol;
  const int ldsw = w * 1024;

  const int arow = wm * 64 + l15;
  const int brow = wn * 64 + l15;
  const int x7 = l15 & 7;
  const int sw0 = (quad ^ x7) << 4;
  const int sw1 = ((4 | quad) ^ x7) << 4;

  f32x4 zero = {0.f, 0.f, 0.f, 0.f};
  f32x4 acc[4][4];
  #pragma unroll
  for (int a = 0; a < 4; ++a)
    #pragma unroll
    for (int b = 0; b < 4; ++b) acc[a][b] = zero;

  {
    char* b0 = smem;
    char* b1 = smem + 49152;
    #pragma unroll
    for (int j = 0; j < 4; ++j) gl2lds16(gA + (size_t)j * 64 * K, b0 + j * 8192 + ldsw);
    #pragma unroll
    for (int j = 0; j < 2; ++j) gl2lds16(gB + (size_t)j * 64 * K, b0 + 32768 + j * 8192 + ldsw);
    #pragma unroll
    for (int j = 0; j < 4; ++j) gl2lds16(gA + 64 + (size_t)j * 64 * K, b1 + j * 8192 + ldsw);
    #pragma unroll
    for (int j = 0; j < 2; ++j) gl2lds16(gB + 64 + (size_t)j * 64 * K, b1 + 32768 + j * 8192 + ldsw);
  }
  asm volatile("s_waitcnt vmcnt(6)" ::: "memory");
  __builtin_amdgcn_sched_barrier(0);
  __builtin_amdgcn_s_barrier();

  int cur = 0, pre = 2;
  for (int t = 0; t < NT; ++t) {
    const char* Ab = smem + cur * 49152;
    const char* Bb = Ab + 32768;
    char* Pb = smem + pre * 49152;
    const bool pf = (t + 2) < NT;
    f16x8 af[4], af1[4], bf[4][2];

    #pragma unroll
    for (int mi = 0; mi < 4; ++mi)
      af[mi] = *(const f16x8*)(Ab + (arow + mi * 16) * 128 + sw0);
    #pragma unroll
    for (int mi = 0; mi < 4; ++mi)
      af1[mi] = *(const f16x8*)(Ab + (arow + mi * 16) * 128 + sw1);
    #pragma unroll
    for (int ni = 0; ni < 2; ++ni) {
      bf[ni][0] = *(const f16x8*)(Bb + (brow + ni * 16) * 128 + sw0);
      bf[ni][1] = *(const f16x8*)(Bb + (brow + ni * 16) * 128 + sw1);
    }
    if (pf) {
      const h16* g = gA + (size_t)(t + 2) * 64;
      #pragma unroll
      for (int j = 0; j < 4; ++j) gl2lds16(g + (size_t)j * 64 * K, Pb + j * 8192 + ldsw);
    }
    __builtin_amdgcn_s_barrier();
    __builtin_amdgcn_s_setprio(1);
    #pragma unroll
    for (int mi = 0; mi < 4; ++mi)
      #pragma unroll
      for (int ni = 0; ni < 2; ++ni) {
        acc[mi][ni] = __builtin_amdgcn_mfma_f32_16x16x32_f16(bf[ni][0], af[mi], acc[mi][ni], 0, 0, 0);
        acc[mi][ni] = __builtin_amdgcn_mfma_f32_16x16x32_f16(bf[ni][1], af1[mi], acc[mi][ni], 0, 0, 0);
      }
    __builtin_amdgcn_s_setprio(0);
    __builtin_amdgcn_s_barrier();

    #pragma unroll
    for (int ni = 2; ni < 4; ++ni) {
      bf[ni][0] = *(const f16x8*)(Bb + (brow + ni * 16) * 128 + sw0);
      bf[ni][1] = *(const f16x8*)(Bb + (brow + ni * 16) * 128 + sw1);
    }
    if (pf) {
      const h16* g = gB + (size_t)(t + 2) * 64;
      #pragma unroll
      for (int j = 0; j < 2; ++j) gl2lds16(g + (size_t)j * 64 * K, Pb + 32768 + j * 8192 + ldsw);
    }
    __builtin_amdgcn_s_barrier();
    __builtin_amdgcn_s_setprio(1);
    #pragma unroll
    for (int mi = 0; mi < 4; ++mi)
      #pragma unroll
      for (int ni = 2; ni < 4; ++ni) {
        acc[mi][ni] = __builtin_amdgcn_mfma_f32_16x16x32_f16(bf[ni][0], af[mi], acc[mi][ni], 0, 0, 0);
        acc[mi][ni] = __builtin_amdgcn_mfma_f32_16x16x32_f16(bf[ni][1], af1[mi], acc[mi][ni], 0, 0, 0);
      }
    __builtin_amdgcn_s_setprio(0);
    if (pf) {
      asm volatile("s_waitcnt vmcnt(6)" ::: "memory");
    } else if (t + 2 == NT) {
      asm volatile("s_waitcnt vmcnt(0)" ::: "memory");
    }
    __builtin_amdgcn_sched_barrier(0);
    __builtin_amdgcn_s_barrier();
    cur = (cur == 2) ? 0 : cur + 1;
    pre = (pre == 2) ? 0 : pre + 1;
  }

  #pragma unroll
  for (int mi = 0; mi < 4; ++mi) {
    const int r = m0 + wm * 64 + mi * 16 + l15;
    #pragma unroll
    for (int ni = 0; ni < 4; ++ni) {
      const int c = n0 + wn * 64 + ni * 16 + quad * 4;
      epi_store4<MODE>(acc[mi][ni], bias, res, out, (size_t)r * N + c, c);
    }
  }
}

// ---------------- Flash attention (no-max softmax): qkv f16 -> ctx f16 --------------
__global__ __launch_bounds__(256, 2) void attn_kernel(
    const h16* __restrict__ qkv, h16* __restrict__ ctx)
{
  const int qb = blockIdx.x;
  const int bh = blockIdx.y;
  const int b = bh >> 4, h = bh & 15;
  const int tid = threadIdx.x;
  const int w = tid >> 6, lane = tid & 63;
  const int l15 = lane & 15, quad = lane >> 4;

  __shared__ __align__(16) h16 Ks[64 * 80];
  __shared__ __align__(16) h16 Vt[64 * 80];
  __shared__ __align__(16) h16 Ps[256 * 80];

  const size_t qrow0 = (size_t)(b * 1024 + qb * 256);
  for (int c = tid; c < 2048; c += 256) {
    const int row = c >> 3, kc = (c & 7) * 8;
    uint4 raw = *(const uint4*)(qkv + (qrow0 + row) * 3072 + h * 64 + kc);
    union { uint4 v; h16 e[8]; } in4, out4;
    in4.v = raw;
    #pragma unroll
    for (int i = 0; i < 8; ++i) out4.e[i] = in4.e[i] * (h16)0.125f;
    *(uint4*)&Ps[row * 80 + kc] = out4.v;
  }
  __syncthreads();
  f16x8 aq[4][2];
  #pragma unroll
  for (int r = 0; r < 4; ++r)
    #pragma unroll
    for (int s = 0; s < 2; ++s)
      aq[r][s] = *(const f16x8*)&Ps[(w * 64 + r * 16 + l15) * 80 + s * 32 + quad * 8];

  f32x4 zero = {0.f, 0.f, 0.f, 0.f};
  f32x4 o_acc[4][4];
  float l_p[4][4];
  #pragma unroll
  for (int r = 0; r < 4; ++r)
    #pragma unroll
    for (int i = 0; i < 4; ++i) { o_acc[r][i] = zero; l_p[r][i] = 0.f; }

  h16* Pw = &Ps[w * 64 * 80];

  for (int jt = 0; jt < 16; ++jt) {
    __syncthreads();
    const size_t kv0 = (size_t)(b * 1024 + jt * 64);
    for (int c = tid; c < 512; c += 256) {
      const int row = c >> 3, kc = (c & 7) * 8;
      *(uint4*)&Ks[row * 80 + kc] =
          *(const uint4*)(qkv + (kv0 + row) * 3072 + 1024 + h * 64 + kc);
    }
    #pragma unroll
    for (int cc = 0; cc < 2; ++cc) {
      const int d0 = (w + cc * 4) * 8;
      uint4 raw = *(const uint4*)(qkv + (kv0 + lane) * 3072 + 2048 + h * 64 + d0);
      union { uint4 v; h16 e[8]; } in4;
      in4.v = raw;
      #pragma unroll
      for (int i = 0; i < 8; ++i) Vt[(d0 + i) * 80 + lane] = in4.e[i];
    }
    __syncthreads();

    f16x8 kf[4][2];
    #pragma unroll
    for (int ni = 0; ni < 4; ++ni)
      #pragma unroll
      for (int s = 0; s < 2; ++s)
        kf[ni][s] = *(const f16x8*)&Ks[(ni * 16 + l15) * 80 + s * 32 + quad * 8];
    #pragma unroll
    for (int r = 0; r < 4; ++r) {
      f32x4 s_acc[4];
      #pragma unroll
      for (int i = 0; i < 4; ++i) s_acc[i] = zero;
      #pragma unroll
      for (int ni = 0; ni < 4; ++ni)
        #pragma unroll
        for (int s = 0; s < 2; ++s)
          s_acc[ni] = __builtin_amdgcn_mfma_f32_16x16x32_f16(aq[r][s], kf[ni][s], s_acc[ni], 0, 0, 0);
      #pragma unroll
      for (int ni = 0; ni < 4; ++ni)
        #pragma unroll
        for (int i = 0; i < 4; ++i) {
          float p = __expf(s_acc[ni][i]);
          l_p[r][i] += p;
          Pw[(r * 16 + quad * 4 + i) * 80 + ni * 16 + l15] = (h16)p;
        }
    }

    f16x8 vf[4][2];
    #pragma unroll
    for (int ni = 0; ni < 4; ++ni)
      #pragma unroll
      for (int s = 0; s < 2; ++s)
        vf[ni][s] = *(const f16x8*)&Vt[(ni * 16 + l15) * 80 + s * 32 + quad * 8];
    #pragma unroll
    for (int r = 0; r < 4; ++r) {
      f16x8 ap0 = *(const f16x8*)&Pw[(r * 16 + l15) * 80 + quad * 8];
      f16x8 ap1 = *(const f16x8*)&Pw[(r * 16 + l15) * 80 + 32 + quad * 8];
      #pragma unroll
      for (int ni = 0; ni < 4; ++ni) {
        o_acc[r][ni] = __builtin_amdgcn_mfma_f32_16x16x32_f16(ap0, vf[ni][0], o_acc[r][ni], 0, 0, 0);
        o_acc[r][ni] = __builtin_amdgcn_mfma_f32_16x16x32_f16(ap1, vf[ni][1], o_acc[r][ni], 0, 0, 0);
      }
    }
  }

  #pragma unroll
  for (int r = 0; r < 4; ++r)
    #pragma unroll
    for (int i = 0; i < 4; ++i) {
      float lt = l_p[r][i];
      #pragma unroll
      for (int off = 1; off < 16; off <<= 1) lt += __shfl_xor(lt, off);
      const float rinv = 1.0f / lt;
      const size_t row = qrow0 + w * 64 + r * 16 + quad * 4 + i;
      #pragma unroll
      for (int ni = 0; ni < 4; ++ni)
        ctx[row * 1024 + h * 64 + ni * 16 + l15] = (h16)(o_acc[r][ni][i] * rinv);
    }
}

// ---------------- launcher ----------------
extern "C" void kernel_launch(void* const* d_in, const int* in_sizes, int n_in,
                              void* d_out, int out_size, void* d_ws, size_t ws_size,
                              hipStream_t stream) {
  const float* x   = (const float*)d_in[0];
  const float* Wq  = (const float*)d_in[1];
  const float* bq  = (const float*)d_in[2];
  const float* Wk  = (const float*)d_in[3];
  const float* bk  = (const float*)d_in[4];
  const float* Wv  = (const float*)d_in[5];
  const float* bv  = (const float*)d_in[6];
  const float* Wo  = (const float*)d_in[7];
  const float* bo  = (const float*)d_in[8];
  const float* g1  = (const float*)d_in[9];
  const float* be1 = (const float*)d_in[10];
  const float* g2  = (const float*)d_in[11];
  const float* be2 = (const float*)d_in[12];
  const float* W1  = (const float*)d_in[13];
  const float* c1  = (const float*)d_in[14];
  const float* W2  = (const float*)d_in[15];
  const float* c2  = (const float*)d_in[16];

  char* ws = (char*)d_ws;
  h16*   WqkvT = (h16*)(ws + 0);
  h16*   WoT   = (h16*)(ws + 6291456);
  h16*   W1T   = (h16*)(ws + 8388608);
  h16*   W2T   = (h16*)(ws + 16777216);
  float* bqkv  = (float*)(ws + 25165824);
  h16*   bufA  = (h16*)(ws + 25178112);    // xn1 / ctx / xn2
  h16*   qkv   = (h16*)(ws + 41955328);
  h16*   x1    = (h16*)(ws + 41955328);    // aliases dead qkv
  h16*   hbuf  = (h16*)(ws + 58732544);

  static bool attr_done = false;
  if (!attr_done) {
    hipFuncSetAttribute((const void*)gemm_bt<1>, hipFuncAttributeMaxDynamicSharedMemorySize, GEMM_LDS);
    hipFuncSetAttribute((const void*)gemm_bt<3>, hipFuncAttributeMaxDynamicSharedMemorySize, GEMM_LDS);
    hipFuncSetAttribute((const void*)gemm201<0>, hipFuncAttributeMaxDynamicSharedMemorySize, GEMM201_LDS);
    hipFuncSetAttribute((const void*)gemm201<2>, hipFuncAttributeMaxDynamicSharedMemorySize, GEMM201_LDS);
    attr_done = true;
  }

  repack_kernel<<<dim3(3073), dim3(256), 0, stream>>>(Wq, Wk, Wv, Wo, W1, W2, bq, bk, bv,
                                                      WqkvT, WoT, W1T, W2T, bqkv);
  ln_kernel<0><<<dim3(8192), dim3(256), 0, stream>>>(x, g1, be1, bufA);        // xn1
  gemm201<0><<<dim3(12, 32), dim3(512), GEMM201_LDS, stream>>>(bufA, WqkvT, bqkv, nullptr, qkv,
                                                               8192, 3072, 1024);
  attn_kernel<<<dim3(4, 128), dim3(256), 0, stream>>>(qkv, bufA);              // ctx
  gemm_bt<1><<<dim3(8, 32), dim3(512), GEMM_LDS, stream>>>(bufA, WoT, bo, x, x1,
                                                           8192, 1024, 1024);
  ln_kernel<1><<<dim3(8192), dim3(256), 0, stream>>>(x1, g2, be2, bufA);       // xn2
  gemm201<2><<<dim3(16, 32), dim3(512), GEMM201_LDS, stream>>>(bufA, W1T, c1, nullptr, hbuf,
                                                               8192, 4096, 1024);
  gemm_bt<3><<<dim3(8, 32), dim3(512), GEMM_LDS, stream>>>(hbuf, W2T, c2, x1, d_out,
                                                           8192, 1024, 4096);
}

// Round 10
// 486.067 us; speedup vs baseline: 1.0439x; 1.0270x over previous
//
#include <hip/hip_runtime.h>
#include <math.h>

// Round 19: RESUBMISSION of round-18 (infra: "MI355X container failed twice",
// broker-outage signature, 3rd occurrence this session — no pytest/profile ran;
// content unindicted). Round-18 content, unchanged:
//  - r5 base (best verified, 482.9us); (b) operand-swap reverted (r8: neutral).
//  - gemm201n = r14's verified 8-phase cadence at 256x128 tile, 8 waves 4Mx2N
//    (64x64/wave), BK=64, LDS 2x48KB, same 8-slot row-XOR swizzle (rows 128B).
//    B halves are 64 rows = 1 gl2lds (A halves 2) -> 6 loads/tile, counted
//    waits become vmcnt(5). Audit: entering P1 in-flight = tile-O's 5;
//    P1+1,P3+2,P4+3 -> 11 = [Ox6, E+2x5]; vmcnt(5) drains exactly tile O;
//    symmetric at P8; peel vmcnt(0). Stage slots = r14's (after last read).
//  - Wo: grid 8x32=256 blocks (exact CU fill), NI=8. MLP2: K=4096, NI=32 —
//    deep pipeline amortizes prologue/peel 8x better than MLP1's NI=4.
// gemm201 (QKV/MLP1) / repack / LN / attention verbatim from r5.

typedef _Float16 h16;
typedef __attribute__((ext_vector_type(8))) _Float16 f16x8;
typedef __attribute__((ext_vector_type(4))) float f32x4;

__device__ __forceinline__ void gl2lds16(const void* g, void* l) {
  __builtin_amdgcn_global_load_lds(
      (const __attribute__((address_space(1))) void*)g,
      (__attribute__((address_space(3))) void*)l, 16, 0, 0);
}

// ---------------- repack: tiled transpose fp32 -> f16 [N][K], + bias pack ----------
__global__ __launch_bounds__(256) void repack_kernel(
    const float* __restrict__ Wq, const float* __restrict__ Wk,
    const float* __restrict__ Wv, const float* __restrict__ Wo,
    const float* __restrict__ W1, const float* __restrict__ W2,
    const float* __restrict__ bq, const float* __restrict__ bk,
    const float* __restrict__ bv,
    h16* __restrict__ WqkvT, h16* __restrict__ WoT, h16* __restrict__ W1T,
    h16* __restrict__ W2T, float* __restrict__ bqkv)
{
  const int t = blockIdx.x;
  const int tid = threadIdx.x;
  if (t == 3072) {
    for (int i = tid; i < 3072; i += 256)
      bqkv[i] = (i < 1024) ? bq[i] : (i < 2048 ? bk[i - 1024] : bv[i - 2048]);
    return;
  }
  __shared__ float ld[64 * 65];

  const float* src; h16* dst;
  int sRS, dRS, k0, sn0, dn0;
  if (t < 768) {
    const int m = t >> 8, tt = t & 255, h = tt >> 4, tk = tt & 15;
    src = ((m == 0) ? Wq : (m == 1) ? Wk : Wv) + (size_t)h * 65536;
    dst = WqkvT; sRS = 64; dRS = 1024;
    k0 = tk * 64; sn0 = 0; dn0 = m * 1024 + h * 64;
  } else if (t < 1024) {
    const int tt = t - 768, tk = tt >> 4, tn = tt & 15;
    src = Wo; dst = WoT; sRS = 1024; dRS = 1024;
    k0 = tk * 64; sn0 = tn * 64; dn0 = tn * 64;
  } else if (t < 2048) {
    const int tt = t - 1024, tk = tt >> 6, tn = tt & 63;
    src = W1; dst = W1T; sRS = 4096; dRS = 1024;
    k0 = tk * 64; sn0 = tn * 64; dn0 = tn * 64;
  } else {
    const int tt = t - 2048, tk = tt >> 4, tn = tt & 15;
    src = W2; dst = W2T; sRS = 1024; dRS = 4096;
    k0 = tk * 64; sn0 = tn * 64; dn0 = tn * 64;
  }

  #pragma unroll
  for (int p = 0; p < 16; ++p) {
    const int idx = p * 256 + tid;
    const int r = idx >> 6, c = idx & 63;
    ld[c * 65 + r] = src[(size_t)(k0 + r) * sRS + sn0 + c];
  }
  __syncthreads();
  #pragma unroll
  for (int p = 0; p < 8; ++p) {
    const int idx = p * 512 + tid * 2;
    const int n = idx >> 6, k = idx & 63;
    union { unsigned int u; h16 e[2]; } pk;
    pk.e[0] = (h16)ld[n * 65 + k];
    pk.e[1] = (h16)ld[n * 65 + k + 1];
    *(unsigned int*)&dst[(size_t)(dn0 + n) * dRS + k0 + k] = pk.u;
  }
}

// ---------------- LayerNorm: (IT==0: fp32 in, IT==1: f16 in) -> f16 out ------------
template <int IT>
__global__ __launch_bounds__(256) void ln_kernel(
    const void* __restrict__ in, const float* __restrict__ gw,
    const float* __restrict__ bw, h16* __restrict__ outp)
{
  const int row = blockIdx.x;
  const int tid = threadIdx.x;
  float v[4];
  if (IT == 0) {
    const float* p = (const float*)in + (size_t)row * 1024 + tid * 4;
    float4 tt = *(const float4*)p;
    v[0] = tt.x; v[1] = tt.y; v[2] = tt.z; v[3] = tt.w;
  } else {
    const h16* p = (const h16*)in + (size_t)row * 1024 + tid * 4;
    union { uint2 u; h16 h[4]; } raw;
    raw.u = *(const uint2*)p;
    v[0] = (float)raw.h[0]; v[1] = (float)raw.h[1];
    v[2] = (float)raw.h[2]; v[3] = (float)raw.h[3];
  }
  float s = v[0] + v[1] + v[2] + v[3];
  float ss = v[0]*v[0] + v[1]*v[1] + v[2]*v[2] + v[3]*v[3];
  #pragma unroll
  for (int off = 32; off >= 1; off >>= 1) {
    s += __shfl_down(s, off);
    ss += __shfl_down(ss, off);
  }
  __shared__ float red[8];
  const int w = tid >> 6;
  if ((tid & 63) == 0) { red[w] = s; red[4 + w] = ss; }
  __syncthreads();
  s = red[0] + red[1] + red[2] + red[3];
  ss = red[4] + red[5] + red[6] + red[7];
  const float mean = s * (1.0f / 1024.0f);
  const float var = ss * (1.0f / 1024.0f) - mean * mean;
  const float inv = rsqrtf(fmaxf(var, 0.0f) + 1e-5f);
  union { uint2 u; h16 h[4]; } pk;
  #pragma unroll
  for (int i = 0; i < 4; ++i)
    pk.h[i] = (h16)((v[i] - mean) * inv * gw[tid * 4 + i] + bw[tid * 4 + i]);
  *(uint2*)(outp + (size_t)row * 1024 + tid * 4) = pk.u;
}

// ================= gemm201: m201 8-phase, 256x256, BK=64, 2 tiles/iter =============
#define GEMM201_LDS 131072

template <int MODE>
__global__ __launch_bounds__(512, 2) void gemm201(
    const h16* __restrict__ A, const h16* __restrict__ BT,
    const float* __restrict__ bias, const void* __restrict__ res,
    void* __restrict__ out, int M, int N, int K)
{
  extern __shared__ __align__(16) char smem[];
  const int tid = threadIdx.x;
  const int lane = tid & 63, w = tid >> 6;
  const int l15 = lane & 15, quad = lane >> 4;
  const int wr = w >> 2, wc = w & 3;               // 2M x 4N waves, 128x64 each
  const int m0 = blockIdx.y * 256, n0 = blockIdx.x * 256;
  const int NI = K >> 7;                           // iterations (2 K-tiles each)

  const int sr = tid >> 3;
  const int sk = ((tid & 7) ^ (sr & 7)) * 8;
  const h16* gAs = A + (size_t)(m0 + sr) * K + sk;
  const h16* gBs = BT + (size_t)(n0 + sr) * K + sk;
  const int dst0 = tid * 16;

  const int x7 = l15 & 7;
  const int sw0 = (quad ^ x7) << 4;
  const int sw1 = ((4 + quad) ^ x7) << 4;
  const int aBase = wr * 16384;
  const int bBase = 32768 + (wc >> 1) * 16384;
  const int bRow0 = (wc & 1) * 64;

  f32x4 zero = {0.f, 0.f, 0.f, 0.f};
  f32x4 acc[8][4];
  #pragma unroll
  for (int a = 0; a < 8; ++a)
    #pragma unroll
    for (int b = 0; b < 4; ++b) acc[a][b] = zero;

  f16x8 AF0[4][2], AF1[4][2], BF0[2][2], BF1[2][2];

  auto rdA = [&](int bufo, int mi0, f16x8 (&AF)[4][2]) {
    #pragma unroll
    for (int mi = 0; mi < 4; ++mi) {
      const char* p = smem + bufo + aBase + ((mi0 + mi) * 16 + l15) * 128;
      AF[mi][0] = *(const f16x8*)(p + sw0);
      AF[mi][1] = *(const f16x8*)(p + sw1);
    }
  };
  auto rdB = [&](int bufo, int ni0, f16x8 (&BF)[2][2]) {
    #pragma unroll
    for (int ni = 0; ni < 2; ++ni) {
      const char* p = smem + bufo + bBase + (bRow0 + (ni0 + ni) * 16 + l15) * 128;
      BF[ni][0] = *(const f16x8*)(p + sw0);
      BF[ni][1] = *(const f16x8*)(p + sw1);
    }
  };
  auto mmq = [&](int mi0, int ni0, f16x8 (&AF)[4][2], f16x8 (&BF)[2][2]) {
    __builtin_amdgcn_s_setprio(1);
    #pragma unroll
    for (int mi = 0; mi < 4; ++mi)
      #pragma unroll
      for (int ni = 0; ni < 2; ++ni) {
        acc[mi0 + mi][ni0 + ni] = __builtin_amdgcn_mfma_f32_16x16x32_f16(
            AF[mi][0], BF[ni][0], acc[mi0 + mi][ni0 + ni], 0, 0, 0);
        acc[mi0 + mi][ni0 + ni] = __builtin_amdgcn_mfma_f32_16x16x32_f16(
            AF[mi][1], BF[ni][1], acc[mi0 + mi][ni0 + ni], 0, 0, 0);
      }
    __builtin_amdgcn_s_setprio(0);
  };

#define STG_A(b, h, T) { \
    char* d_ = smem + (b) * 65536 + (h) * 16384 + dst0; \
    const h16* g_ = gAs + (size_t)((h) * 128) * K + (size_t)(T) * 64; \
    gl2lds16(g_, d_); gl2lds16(g_ + (size_t)64 * K, d_ + 8192); }
#define STG_B(b, h, T) { \
    char* d_ = smem + (b) * 65536 + 32768 + (h) * 16384 + dst0; \
    const h16* g_ = gBs + (size_t)((h) * 128) * K + (size_t)(T) * 64; \
    gl2lds16(g_, d_); gl2lds16(g_ + (size_t)64 * K, d_ + 8192); }
#define BAR __builtin_amdgcn_s_barrier()
#define VMC(n) { asm volatile("s_waitcnt vmcnt(" #n ")" ::: "memory"); \
                 __builtin_amdgcn_sched_barrier(0); }

  // ---- prologue: tile0 (4 halves) + tile1 {Ah0, Ah1, Bh0} ----
  STG_A(0, 0, 0); STG_A(0, 1, 0); STG_B(0, 0, 0); STG_B(0, 1, 0);
  STG_A(1, 0, 1); STG_A(1, 1, 1); STG_B(1, 0, 1);
  VMC(6);
  BAR;

  for (int i = 0; i < NI - 1; ++i) {
    const int E = 2 * i, O = E + 1;
    // P1
    rdA(0, 0, AF0); rdB(0, 0, BF0);
    STG_B(1, 1, O);
    BAR; mmq(0, 0, AF0, BF0); BAR;
    // P2 (buf0 A last read)
    rdA(0, 4, AF1);
    BAR; mmq(4, 0, AF1, BF0); BAR;
    // P3 (buf0 B last read); stage Ah0(E+2)
    rdB(0, 2, BF1);
    STG_A(0, 0, E + 2);
    BAR; mmq(4, 2, AF1, BF1); BAR;
    // P4 (pure compute): stage remaining buf0 halves, counted wait
    STG_A(0, 1, E + 2); STG_B(0, 0, E + 2);
    VMC(6);
    BAR; mmq(0, 2, AF0, BF1); BAR;
    // P5
    rdA(65536, 0, AF0); rdB(65536, 0, BF0);
    STG_B(0, 1, E + 2);
    BAR; mmq(0, 0, AF0, BF0); BAR;
    // P6 (buf1 A last read)
    rdA(65536, 4, AF1);
    BAR; mmq(4, 0, AF1, BF0); BAR;
    // P7 (buf1 B last read); stage Ah0(O+2)
    rdB(65536, 2, BF1);
    STG_A(1, 0, O + 2);
    BAR; mmq(4, 2, AF1, BF1); BAR;
    // P8
    STG_A(1, 1, O + 2); STG_B(1, 0, O + 2);
    VMC(6);
    BAR; mmq(0, 2, AF0, BF1); BAR;
  }

  // ---- peeled final iteration: only Bh1(O) staged ----
  {
    const int O = 2 * NI - 1;
    rdA(0, 0, AF0); rdB(0, 0, BF0);
    STG_B(1, 1, O);
    BAR; mmq(0, 0, AF0, BF0); BAR;
    rdA(0, 4, AF1);
    BAR; mmq(4, 0, AF1, BF0); BAR;
    rdB(0, 2, BF1);
    BAR; mmq(4, 2, AF1, BF1); BAR;
    VMC(0);
    BAR; mmq(0, 2, AF0, BF1); BAR;
    rdA(65536, 0, AF0); rdB(65536, 0, BF0);
    BAR; mmq(0, 0, AF0, BF0); BAR;
    rdA(65536, 4, AF1);
    BAR; mmq(4, 0, AF1, BF0); BAR;
    rdB(65536, 2, BF1);
    BAR; mmq(4, 2, AF1, BF1); BAR;
    mmq(0, 2, AF0, BF1);
  }

  // ---- epilogue ----
  #pragma unroll
  for (int mi = 0; mi < 8; ++mi) {
    #pragma unroll
    for (int ni = 0; ni < 4; ++ni) {
      #pragma unroll
      for (int i = 0; i < 4; ++i) {
        const int r = m0 + wr * 128 + mi * 16 + quad * 4 + i;
        const int c = n0 + wc * 64 + ni * 16 + l15;
        const size_t idx = (size_t)r * N + c;
        float v = acc[mi][ni][i] + bias[c];
        if (MODE == 0) {
          ((h16*)out)[idx] = (h16)v;
        } else if (MODE == 1) {
          v += ((const float*)res)[idx];
          ((h16*)out)[idx] = (h16)v;
        } else if (MODE == 2) {
          const float e = __expf(v * (-1.5957691216f - 0.0713548163f * v * v));
          v = v / (1.0f + e);
          ((h16*)out)[idx] = (h16)v;
        } else {
          v += (float)((const h16*)res)[idx];
          ((float*)out)[idx] = v;
        }
      }
    }
  }
#undef STG_A
#undef STG_B
}

// ========== gemm201n: 8-phase, 256x128 tile, 8 waves 4Mx2N (64x64), BK=64 ==========
// r14 cadence with 6-load tiles (A halves 2 gl2lds, B halves 1) -> vmcnt(5).
#define GEMM201N_LDS 98304

template <int MODE>
__global__ __launch_bounds__(512, 2) void gemm201n(
    const h16* __restrict__ A, const h16* __restrict__ BT,
    const float* __restrict__ bias, const void* __restrict__ res,
    void* __restrict__ out, int M, int N, int K)
{
  extern __shared__ __align__(16) char smem[];
  const int tid = threadIdx.x;
  const int lane = tid & 63, w = tid >> 6;
  const int l15 = lane & 15, quad = lane >> 4;
  const int wr = w >> 1, wc = w & 1;               // 4M x 2N waves, 64x64 each
  const int m0 = blockIdx.y * 256, n0 = blockIdx.x * 128;
  const int NI = K >> 7;                           // iterations (2 K-tiles each)

  const int sr = tid >> 3;
  const int sk = ((tid & 7) ^ (sr & 7)) * 8;
  const h16* gAs = A + (size_t)(m0 + sr) * K + sk;
  const h16* gBs = BT + (size_t)(n0 + sr) * K + sk;
  const int dst0 = tid * 16;

  const int x7 = l15 & 7;
  const int sw0 = (quad ^ x7) << 4;
  const int sw1 = ((4 + quad) ^ x7) << 4;
  const int aBase = wr * 8192;                     // A region 32KB, 64 rows/wave
  const int bBase = 32768 + wc * 8192;             // B region 16KB, 64 rows/wave

  f32x4 zero = {0.f, 0.f, 0.f, 0.f};
  f32x4 acc[4][4];
  #pragma unroll
  for (int a = 0; a < 4; ++a)
    #pragma unroll
    for (int b = 0; b < 4; ++b) acc[a][b] = zero;

  f16x8 AF0[2][2], AF1[2][2], BF0[2][2], BF1[2][2];

  auto rdA = [&](int bufo, int mi0, f16x8 (&AF)[2][2]) {
    #pragma unroll
    for (int mi = 0; mi < 2; ++mi) {
      const char* p = smem + bufo + aBase + ((mi0 + mi) * 16 + l15) * 128;
      AF[mi][0] = *(const f16x8*)(p + sw0);
      AF[mi][1] = *(const f16x8*)(p + sw1);
    }
  };
  auto rdB = [&](int bufo, int ni0, f16x8 (&BF)[2][2]) {
    #pragma unroll
    for (int ni = 0; ni < 2; ++ni) {
      const char* p = smem + bufo + bBase + ((ni0 + ni) * 16 + l15) * 128;
      BF[ni][0] = *(const f16x8*)(p + sw0);
      BF[ni][1] = *(const f16x8*)(p + sw1);
    }
  };
  auto mmq = [&](int mi0, int ni0, f16x8 (&AF)[2][2], f16x8 (&BF)[2][2]) {
    __builtin_amdgcn_s_setprio(1);
    #pragma unroll
    for (int mi = 0; mi < 2; ++mi)
      #pragma unroll
      for (int ni = 0; ni < 2; ++ni) {
        acc[mi0 + mi][ni0 + ni] = __builtin_amdgcn_mfma_f32_16x16x32_f16(
            AF[mi][0], BF[ni][0], acc[mi0 + mi][ni0 + ni], 0, 0, 0);
        acc[mi0 + mi][ni0 + ni] = __builtin_amdgcn_mfma_f32_16x16x32_f16(
            AF[mi][1], BF[ni][1], acc[mi0 + mi][ni0 + ni], 0, 0, 0);
      }
    __builtin_amdgcn_s_setprio(0);
  };

  // buffer stride 48KB; A halves = 128 rows (16KB, 2 loads); B halves = 64 rows (8KB, 1).
#define STG_A(b, h, T) { \
    char* d_ = smem + (b) * 49152 + (h) * 16384 + dst0; \
    const h16* g_ = gAs + (size_t)((h) * 128) * K + (size_t)(T) * 64; \
    gl2lds16(g_, d_); gl2lds16(g_ + (size_t)64 * K, d_ + 8192); }
#define STG_B(b, h, T) { \
    char* d_ = smem + (b) * 49152 + 32768 + (h) * 8192 + dst0; \
    const h16* g_ = gBs + (size_t)((h) * 64) * K + (size_t)(T) * 64; \
    gl2lds16(g_, d_); }

  // ---- prologue: tile0 (6 loads) + tile1 {Ah0, Ah1, Bh0} (5 loads) ----
  STG_A(0, 0, 0); STG_A(0, 1, 0); STG_B(0, 0, 0); STG_B(0, 1, 0);
  STG_A(1, 0, 1); STG_A(1, 1, 1); STG_B(1, 0, 1);
  VMC(5);                                          // tile0 resident; 5 in flight
  BAR;

  for (int i = 0; i < NI - 1; ++i) {
    const int E = 2 * i, O = E + 1;
    // P1
    rdA(0, 0, AF0); rdB(0, 0, BF0);
    STG_B(1, 1, O);
    BAR; mmq(0, 0, AF0, BF0); BAR;
    // P2 (buf0 A last read)
    rdA(0, 2, AF1);
    BAR; mmq(2, 0, AF1, BF0); BAR;
    // P3 (buf0 B last read); stage Ah0(E+2)
    rdB(0, 2, BF1);
    STG_A(0, 0, E + 2);
    BAR; mmq(2, 2, AF1, BF1); BAR;
    // P4: stage Ah1+Bh0(E+2); wait drains tile O's 6 loads
    STG_A(0, 1, E + 2); STG_B(0, 0, E + 2);
    VMC(5);
    BAR; mmq(0, 2, AF0, BF1); BAR;
    // P5
    rdA(49152, 0, AF0); rdB(49152, 0, BF0);
    STG_B(0, 1, E + 2);
    BAR; mmq(0, 0, AF0, BF0); BAR;
    // P6 (buf1 A last read)
    rdA(49152, 2, AF1);
    BAR; mmq(2, 0, AF1, BF0); BAR;
    // P7 (buf1 B last read); stage Ah0(O+2)
    rdB(49152, 2, BF1);
    STG_A(1, 0, O + 2);
    BAR; mmq(2, 2, AF1, BF1); BAR;
    // P8: stage Ah1+Bh0(O+2); wait drains tile E+2's 6 loads
    STG_A(1, 1, O + 2); STG_B(1, 0, O + 2);
    VMC(5);
    BAR; mmq(0, 2, AF0, BF1); BAR;
  }

  // ---- peeled final iteration: only Bh1(O) staged ----
  {
    const int O = 2 * NI - 1;
    rdA(0, 0, AF0); rdB(0, 0, BF0);
    STG_B(1, 1, O);
    BAR; mmq(0, 0, AF0, BF0); BAR;
    rdA(0, 2, AF1);
    BAR; mmq(2, 0, AF1, BF0); BAR;
    rdB(0, 2, BF1);
    BAR; mmq(2, 2, AF1, BF1); BAR;
    VMC(0);
    BAR; mmq(0, 2, AF0, BF1); BAR;
    rdA(49152, 0, AF0); rdB(49152, 0, BF0);
    BAR; mmq(0, 0, AF0, BF0); BAR;
    rdA(49152, 2, AF1);
    BAR; mmq(2, 0, AF1, BF0); BAR;
    rdB(49152, 2, BF1);
    BAR; mmq(2, 2, AF1, BF1); BAR;
    mmq(0, 2, AF0, BF1);
  }

  // ---- epilogue ----
  #pragma unroll
  for (int mi = 0; mi < 4; ++mi) {
    #pragma unroll
    for (int ni = 0; ni < 4; ++ni) {
      #pragma unroll
      for (int i = 0; i < 4; ++i) {
        const int r = m0 + wr * 64 + mi * 16 + quad * 4 + i;
        const int c = n0 + wc * 64 + ni * 16 + l15;
        const size_t idx = (size_t)r * N + c;
        float v = acc[mi][ni][i] + bias[c];
        if (MODE == 0) {
          ((h16*)out)[idx] = (h16)v;
        } else if (MODE == 1) {
          v += ((const float*)res)[idx];
          ((h16*)out)[idx] = (h16)v;
        } else if (MODE == 2) {
          const float e = __expf(v * (-1.5957691216f - 0.0713548163f * v * v));
          v = v / (1.0f + e);
          ((h16*)out)[idx] = (h16)v;
        } else {
          v += (float)((const h16*)res)[idx];
          ((float*)out)[idx] = v;
        }
      }
    }
  }
#undef STG_A
#undef STG_B
#undef BAR
#undef VMC
}

// ---------------- Flash attention (no-max softmax): qkv f16 -> ctx f16 --------------
__global__ __launch_bounds__(256, 2) void attn_kernel(
    const h16* __restrict__ qkv, h16* __restrict__ ctx)
{
  const int qb = blockIdx.x;
  const int bh = blockIdx.y;
  const int b = bh >> 4, h = bh & 15;
  const int tid = threadIdx.x;
  const int w = tid >> 6, lane = tid & 63;
  const int l15 = lane & 15, quad = lane >> 4;

  __shared__ __align__(16) h16 Ks[64 * 80];
  __shared__ __align__(16) h16 Vt[64 * 80];
  __shared__ __align__(16) h16 Ps[256 * 80];

  const size_t qrow0 = (size_t)(b * 1024 + qb * 256);
  for (int c = tid; c < 2048; c += 256) {
    const int row = c >> 3, kc = (c & 7) * 8;
    uint4 raw = *(const uint4*)(qkv + (qrow0 + row) * 3072 + h * 64 + kc);
    union { uint4 v; h16 e[8]; } in4, out4;
    in4.v = raw;
    #pragma unroll
    for (int i = 0; i < 8; ++i) out4.e[i] = in4.e[i] * (h16)0.125f;
    *(uint4*)&Ps[row * 80 + kc] = out4.v;
  }
  __syncthreads();
  f16x8 aq[4][2];
  #pragma unroll
  for (int r = 0; r < 4; ++r)
    #pragma unroll
    for (int s = 0; s < 2; ++s)
      aq[r][s] = *(const f16x8*)&Ps[(w * 64 + r * 16 + l15) * 80 + s * 32 + quad * 8];

  f32x4 zero = {0.f, 0.f, 0.f, 0.f};
  f32x4 o_acc[4][4];
  float l_p[4][4];
  #pragma unroll
  for (int r = 0; r < 4; ++r)
    #pragma unroll
    for (int i = 0; i < 4; ++i) { o_acc[r][i] = zero; l_p[r][i] = 0.f; }

  h16* Pw = &Ps[w * 64 * 80];

  for (int jt = 0; jt < 16; ++jt) {
    __syncthreads();
    const size_t kv0 = (size_t)(b * 1024 + jt * 64);
    for (int c = tid; c < 512; c += 256) {
      const int row = c >> 3, kc = (c & 7) * 8;
      *(uint4*)&Ks[row * 80 + kc] =
          *(const uint4*)(qkv + (kv0 + row) * 3072 + 1024 + h * 64 + kc);
    }
    #pragma unroll
    for (int cc = 0; cc < 2; ++cc) {
      const int d0 = (w + cc * 4) * 8;
      uint4 raw = *(const uint4*)(qkv + (kv0 + lane) * 3072 + 2048 + h * 64 + d0);
      union { uint4 v; h16 e[8]; } in4;
      in4.v = raw;
      #pragma unroll
      for (int i = 0; i < 8; ++i) Vt[(d0 + i) * 80 + lane] = in4.e[i];
    }
    __syncthreads();

    f16x8 kf[4][2];
    #pragma unroll
    for (int ni = 0; ni < 4; ++ni)
      #pragma unroll
      for (int s = 0; s < 2; ++s)
        kf[ni][s] = *(const f16x8*)&Ks[(ni * 16 + l15) * 80 + s * 32 + quad * 8];
    #pragma unroll
    for (int r = 0; r < 4; ++r) {
      f32x4 s_acc[4];
      #pragma unroll
      for (int i = 0; i < 4; ++i) s_acc[i] = zero;
      #pragma unroll
      for (int ni = 0; ni < 4; ++ni)
        #pragma unroll
        for (int s = 0; s < 2; ++s)
          s_acc[ni] = __builtin_amdgcn_mfma_f32_16x16x32_f16(aq[r][s], kf[ni][s], s_acc[ni], 0, 0, 0);
      #pragma unroll
      for (int ni = 0; ni < 4; ++ni)
        #pragma unroll
        for (int i = 0; i < 4; ++i) {
          float p = __expf(s_acc[ni][i]);
          l_p[r][i] += p;
          Pw[(r * 16 + quad * 4 + i) * 80 + ni * 16 + l15] = (h16)p;
        }
    }

    f16x8 vf[4][2];
    #pragma unroll
    for (int ni = 0; ni < 4; ++ni)
      #pragma unroll
      for (int s = 0; s < 2; ++s)
        vf[ni][s] = *(const f16x8*)&Vt[(ni * 16 + l15) * 80 + s * 32 + quad * 8];
    #pragma unroll
    for (int r = 0; r < 4; ++r) {
      f16x8 ap0 = *(const f16x8*)&Pw[(r * 16 + l15) * 80 + quad * 8];
      f16x8 ap1 = *(const f16x8*)&Pw[(r * 16 + l15) * 80 + 32 + quad * 8];
      #pragma unroll
      for (int ni = 0; ni < 4; ++ni) {
        o_acc[r][ni] = __builtin_amdgcn_mfma_f32_16x16x32_f16(ap0, vf[ni][0], o_acc[r][ni], 0, 0, 0);
        o_acc[r][ni] = __builtin_amdgcn_mfma_f32_16x16x32_f16(ap1, vf[ni][1], o_acc[r][ni], 0, 0, 0);
      }
    }
  }

  #pragma unroll
  for (int r = 0; r < 4; ++r)
    #pragma unroll
    for (int i = 0; i < 4; ++i) {
      float lt = l_p[r][i];
      #pragma unroll
      for (int off = 1; off < 16; off <<= 1) lt += __shfl_xor(lt, off);
      const float rinv = 1.0f / lt;
      const size_t row = qrow0 + w * 64 + r * 16 + quad * 4 + i;
      #pragma unroll
      for (int ni = 0; ni < 4; ++ni)
        ctx[row * 1024 + h * 64 + ni * 16 + l15] = (h16)(o_acc[r][ni][i] * rinv);
    }
}

// ---------------- launcher ----------------
extern "C" void kernel_launch(void* const* d_in, const int* in_sizes, int n_in,
                              void* d_out, int out_size, void* d_ws, size_t ws_size,
                              hipStream_t stream) {
  const float* x   = (const float*)d_in[0];
  const float* Wq  = (const float*)d_in[1];
  const float* bq  = (const float*)d_in[2];
  const float* Wk  = (const float*)d_in[3];
  const float* bk  = (const float*)d_in[4];
  const float* Wv  = (const float*)d_in[5];
  const float* bv  = (const float*)d_in[6];
  const float* Wo  = (const float*)d_in[7];
  const float* bo  = (const float*)d_in[8];
  const float* g1  = (const float*)d_in[9];
  const float* be1 = (const float*)d_in[10];
  const float* g2  = (const float*)d_in[11];
  const float* be2 = (const float*)d_in[12];
  const float* W1  = (const float*)d_in[13];
  const float* c1  = (const float*)d_in[14];
  const float* W2  = (const float*)d_in[15];
  const float* c2  = (const float*)d_in[16];

  char* ws = (char*)d_ws;
  h16*   WqkvT = (h16*)(ws + 0);
  h16*   WoT   = (h16*)(ws + 6291456);
  h16*   W1T   = (h16*)(ws + 8388608);
  h16*   W2T   = (h16*)(ws + 16777216);
  float* bqkv  = (float*)(ws + 25165824);
  h16*   bufA  = (h16*)(ws + 25178112);    // xn1 / ctx / xn2
  h16*   qkv   = (h16*)(ws + 41955328);
  h16*   x1    = (h16*)(ws + 41955328);    // aliases dead qkv
  h16*   hbuf  = (h16*)(ws + 58732544);

  static bool attr_done = false;
  if (!attr_done) {
    hipFuncSetAttribute((const void*)gemm201<0>, hipFuncAttributeMaxDynamicSharedMemorySize, GEMM201_LDS);
    hipFuncSetAttribute((const void*)gemm201<2>, hipFuncAttributeMaxDynamicSharedMemorySize, GEMM201_LDS);
    hipFuncSetAttribute((const void*)gemm201n<1>, hipFuncAttributeMaxDynamicSharedMemorySize, GEMM201N_LDS);
    hipFuncSetAttribute((const void*)gemm201n<3>, hipFuncAttributeMaxDynamicSharedMemorySize, GEMM201N_LDS);
    attr_done = true;
  }

  repack_kernel<<<dim3(3073), dim3(256), 0, stream>>>(Wq, Wk, Wv, Wo, W1, W2, bq, bk, bv,
                                                      WqkvT, WoT, W1T, W2T, bqkv);
  ln_kernel<0><<<dim3(8192), dim3(256), 0, stream>>>(x, g1, be1, bufA);        // xn1
  gemm201<0><<<dim3(12, 32), dim3(512), GEMM201_LDS, stream>>>(bufA, WqkvT, bqkv, nullptr, qkv,
                                                               8192, 3072, 1024);
  attn_kernel<<<dim3(4, 128), dim3(256), 0, stream>>>(qkv, bufA);              // ctx
  gemm201n<1><<<dim3(8, 32), dim3(512), GEMM201N_LDS, stream>>>(bufA, WoT, bo, x, x1,
                                                                8192, 1024, 1024);
  ln_kernel<1><<<dim3(8192), dim3(256), 0, stream>>>(x1, g2, be2, bufA);       // xn2
  gemm201<2><<<dim3(16, 32), dim3(512), GEMM201_LDS, stream>>>(bufA, W1T, c1, nullptr, hbuf,
                                                               8192, 4096, 1024);
  gemm201n<3><<<dim3(8, 32), dim3(512), GEMM201N_LDS, stream>>>(hbuf, W2T, c2, x1, d_out,
                                                                8192, 1024, 4096);
}

// Round 11
// 479.973 us; speedup vs baseline: 1.0572x; 1.0127x over previous
//
#include <hip/hip_runtime.h>
#include <math.h>

// Round 20: single change vs r10 (486.1us): QKV moved from gemm201 (256x256,
// grid 12x32=384 blocks = 1.5 CU-rounds -> 2 rounds with half-idle tail) to
// gemm201n (256x128, grid 24x32=768 = 3 EXACT rounds at 1 block/CU).
// Tail model: gemm201-class blocks run 1/CU (128KB LDS); a 384-block dispatch
// costs 2 full rounds (~90us) for 1.5 rounds of work. 768 half-size blocks
// = 3 exact rounds ~= 68us. Launcher-only diff; gemm201n verified in r10.
// All kernels byte-identical to r10.

typedef _Float16 h16;
typedef __attribute__((ext_vector_type(8))) _Float16 f16x8;
typedef __attribute__((ext_vector_type(4))) float f32x4;

__device__ __forceinline__ void gl2lds16(const void* g, void* l) {
  __builtin_amdgcn_global_load_lds(
      (const __attribute__((address_space(1))) void*)g,
      (__attribute__((address_space(3))) void*)l, 16, 0, 0);
}

// ---------------- repack: tiled transpose fp32 -> f16 [N][K], + bias pack ----------
__global__ __launch_bounds__(256) void repack_kernel(
    const float* __restrict__ Wq, const float* __restrict__ Wk,
    const float* __restrict__ Wv, const float* __restrict__ Wo,
    const float* __restrict__ W1, const float* __restrict__ W2,
    const float* __restrict__ bq, const float* __restrict__ bk,
    const float* __restrict__ bv,
    h16* __restrict__ WqkvT, h16* __restrict__ WoT, h16* __restrict__ W1T,
    h16* __restrict__ W2T, float* __restrict__ bqkv)
{
  const int t = blockIdx.x;
  const int tid = threadIdx.x;
  if (t == 3072) {
    for (int i = tid; i < 3072; i += 256)
      bqkv[i] = (i < 1024) ? bq[i] : (i < 2048 ? bk[i - 1024] : bv[i - 2048]);
    return;
  }
  __shared__ float ld[64 * 65];

  const float* src; h16* dst;
  int sRS, dRS, k0, sn0, dn0;
  if (t < 768) {
    const int m = t >> 8, tt = t & 255, h = tt >> 4, tk = tt & 15;
    src = ((m == 0) ? Wq : (m == 1) ? Wk : Wv) + (size_t)h * 65536;
    dst = WqkvT; sRS = 64; dRS = 1024;
    k0 = tk * 64; sn0 = 0; dn0 = m * 1024 + h * 64;
  } else if (t < 1024) {
    const int tt = t - 768, tk = tt >> 4, tn = tt & 15;
    src = Wo; dst = WoT; sRS = 1024; dRS = 1024;
    k0 = tk * 64; sn0 = tn * 64; dn0 = tn * 64;
  } else if (t < 2048) {
    const int tt = t - 1024, tk = tt >> 6, tn = tt & 63;
    src = W1; dst = W1T; sRS = 4096; dRS = 1024;
    k0 = tk * 64; sn0 = tn * 64; dn0 = tn * 64;
  } else {
    const int tt = t - 2048, tk = tt >> 4, tn = tt & 15;
    src = W2; dst = W2T; sRS = 1024; dRS = 4096;
    k0 = tk * 64; sn0 = tn * 64; dn0 = tn * 64;
  }

  #pragma unroll
  for (int p = 0; p < 16; ++p) {
    const int idx = p * 256 + tid;
    const int r = idx >> 6, c = idx & 63;
    ld[c * 65 + r] = src[(size_t)(k0 + r) * sRS + sn0 + c];
  }
  __syncthreads();
  #pragma unroll
  for (int p = 0; p < 8; ++p) {
    const int idx = p * 512 + tid * 2;
    const int n = idx >> 6, k = idx & 63;
    union { unsigned int u; h16 e[2]; } pk;
    pk.e[0] = (h16)ld[n * 65 + k];
    pk.e[1] = (h16)ld[n * 65 + k + 1];
    *(unsigned int*)&dst[(size_t)(dn0 + n) * dRS + k0 + k] = pk.u;
  }
}

// ---------------- LayerNorm: (IT==0: fp32 in, IT==1: f16 in) -> f16 out ------------
template <int IT>
__global__ __launch_bounds__(256) void ln_kernel(
    const void* __restrict__ in, const float* __restrict__ gw,
    const float* __restrict__ bw, h16* __restrict__ outp)
{
  const int row = blockIdx.x;
  const int tid = threadIdx.x;
  float v[4];
  if (IT == 0) {
    const float* p = (const float*)in + (size_t)row * 1024 + tid * 4;
    float4 tt = *(const float4*)p;
    v[0] = tt.x; v[1] = tt.y; v[2] = tt.z; v[3] = tt.w;
  } else {
    const h16* p = (const h16*)in + (size_t)row * 1024 + tid * 4;
    union { uint2 u; h16 h[4]; } raw;
    raw.u = *(const uint2*)p;
    v[0] = (float)raw.h[0]; v[1] = (float)raw.h[1];
    v[2] = (float)raw.h[2]; v[3] = (float)raw.h[3];
  }
  float s = v[0] + v[1] + v[2] + v[3];
  float ss = v[0]*v[0] + v[1]*v[1] + v[2]*v[2] + v[3]*v[3];
  #pragma unroll
  for (int off = 32; off >= 1; off >>= 1) {
    s += __shfl_down(s, off);
    ss += __shfl_down(ss, off);
  }
  __shared__ float red[8];
  const int w = tid >> 6;
  if ((tid & 63) == 0) { red[w] = s; red[4 + w] = ss; }
  __syncthreads();
  s = red[0] + red[1] + red[2] + red[3];
  ss = red[4] + red[5] + red[6] + red[7];
  const float mean = s * (1.0f / 1024.0f);
  const float var = ss * (1.0f / 1024.0f) - mean * mean;
  const float inv = rsqrtf(fmaxf(var, 0.0f) + 1e-5f);
  union { uint2 u; h16 h[4]; } pk;
  #pragma unroll
  for (int i = 0; i < 4; ++i)
    pk.h[i] = (h16)((v[i] - mean) * inv * gw[tid * 4 + i] + bw[tid * 4 + i]);
  *(uint2*)(outp + (size_t)row * 1024 + tid * 4) = pk.u;
}

// ================= gemm201: m201 8-phase, 256x256, BK=64, 2 tiles/iter =============
#define GEMM201_LDS 131072

template <int MODE>
__global__ __launch_bounds__(512, 2) void gemm201(
    const h16* __restrict__ A, const h16* __restrict__ BT,
    const float* __restrict__ bias, const void* __restrict__ res,
    void* __restrict__ out, int M, int N, int K)
{
  extern __shared__ __align__(16) char smem[];
  const int tid = threadIdx.x;
  const int lane = tid & 63, w = tid >> 6;
  const int l15 = lane & 15, quad = lane >> 4;
  const int wr = w >> 2, wc = w & 3;               // 2M x 4N waves, 128x64 each
  const int m0 = blockIdx.y * 256, n0 = blockIdx.x * 256;
  const int NI = K >> 7;                           // iterations (2 K-tiles each)

  const int sr = tid >> 3;
  const int sk = ((tid & 7) ^ (sr & 7)) * 8;
  const h16* gAs = A + (size_t)(m0 + sr) * K + sk;
  const h16* gBs = BT + (size_t)(n0 + sr) * K + sk;
  const int dst0 = tid * 16;

  const int x7 = l15 & 7;
  const int sw0 = (quad ^ x7) << 4;
  const int sw1 = ((4 + quad) ^ x7) << 4;
  const int aBase = wr * 16384;
  const int bBase = 32768 + (wc >> 1) * 16384;
  const int bRow0 = (wc & 1) * 64;

  f32x4 zero = {0.f, 0.f, 0.f, 0.f};
  f32x4 acc[8][4];
  #pragma unroll
  for (int a = 0; a < 8; ++a)
    #pragma unroll
    for (int b = 0; b < 4; ++b) acc[a][b] = zero;

  f16x8 AF0[4][2], AF1[4][2], BF0[2][2], BF1[2][2];

  auto rdA = [&](int bufo, int mi0, f16x8 (&AF)[4][2]) {
    #pragma unroll
    for (int mi = 0; mi < 4; ++mi) {
      const char* p = smem + bufo + aBase + ((mi0 + mi) * 16 + l15) * 128;
      AF[mi][0] = *(const f16x8*)(p + sw0);
      AF[mi][1] = *(const f16x8*)(p + sw1);
    }
  };
  auto rdB = [&](int bufo, int ni0, f16x8 (&BF)[2][2]) {
    #pragma unroll
    for (int ni = 0; ni < 2; ++ni) {
      const char* p = smem + bufo + bBase + (bRow0 + (ni0 + ni) * 16 + l15) * 128;
      BF[ni][0] = *(const f16x8*)(p + sw0);
      BF[ni][1] = *(const f16x8*)(p + sw1);
    }
  };
  auto mmq = [&](int mi0, int ni0, f16x8 (&AF)[4][2], f16x8 (&BF)[2][2]) {
    __builtin_amdgcn_s_setprio(1);
    #pragma unroll
    for (int mi = 0; mi < 4; ++mi)
      #pragma unroll
      for (int ni = 0; ni < 2; ++ni) {
        acc[mi0 + mi][ni0 + ni] = __builtin_amdgcn_mfma_f32_16x16x32_f16(
            AF[mi][0], BF[ni][0], acc[mi0 + mi][ni0 + ni], 0, 0, 0);
        acc[mi0 + mi][ni0 + ni] = __builtin_amdgcn_mfma_f32_16x16x32_f16(
            AF[mi][1], BF[ni][1], acc[mi0 + mi][ni0 + ni], 0, 0, 0);
      }
    __builtin_amdgcn_s_setprio(0);
  };

#define STG_A(b, h, T) { \
    char* d_ = smem + (b) * 65536 + (h) * 16384 + dst0; \
    const h16* g_ = gAs + (size_t)((h) * 128) * K + (size_t)(T) * 64; \
    gl2lds16(g_, d_); gl2lds16(g_ + (size_t)64 * K, d_ + 8192); }
#define STG_B(b, h, T) { \
    char* d_ = smem + (b) * 65536 + 32768 + (h) * 16384 + dst0; \
    const h16* g_ = gBs + (size_t)((h) * 128) * K + (size_t)(T) * 64; \
    gl2lds16(g_, d_); gl2lds16(g_ + (size_t)64 * K, d_ + 8192); }
#define BAR __builtin_amdgcn_s_barrier()
#define VMC(n) { asm volatile("s_waitcnt vmcnt(" #n ")" ::: "memory"); \
                 __builtin_amdgcn_sched_barrier(0); }

  // ---- prologue: tile0 (4 halves) + tile1 {Ah0, Ah1, Bh0} ----
  STG_A(0, 0, 0); STG_A(0, 1, 0); STG_B(0, 0, 0); STG_B(0, 1, 0);
  STG_A(1, 0, 1); STG_A(1, 1, 1); STG_B(1, 0, 1);
  VMC(6);
  BAR;

  for (int i = 0; i < NI - 1; ++i) {
    const int E = 2 * i, O = E + 1;
    // P1
    rdA(0, 0, AF0); rdB(0, 0, BF0);
    STG_B(1, 1, O);
    BAR; mmq(0, 0, AF0, BF0); BAR;
    // P2 (buf0 A last read)
    rdA(0, 4, AF1);
    BAR; mmq(4, 0, AF1, BF0); BAR;
    // P3 (buf0 B last read); stage Ah0(E+2)
    rdB(0, 2, BF1);
    STG_A(0, 0, E + 2);
    BAR; mmq(4, 2, AF1, BF1); BAR;
    // P4 (pure compute): stage remaining buf0 halves, counted wait
    STG_A(0, 1, E + 2); STG_B(0, 0, E + 2);
    VMC(6);
    BAR; mmq(0, 2, AF0, BF1); BAR;
    // P5
    rdA(65536, 0, AF0); rdB(65536, 0, BF0);
    STG_B(0, 1, E + 2);
    BAR; mmq(0, 0, AF0, BF0); BAR;
    // P6 (buf1 A last read)
    rdA(65536, 4, AF1);
    BAR; mmq(4, 0, AF1, BF0); BAR;
    // P7 (buf1 B last read); stage Ah0(O+2)
    rdB(65536, 2, BF1);
    STG_A(1, 0, O + 2);
    BAR; mmq(4, 2, AF1, BF1); BAR;
    // P8
    STG_A(1, 1, O + 2); STG_B(1, 0, O + 2);
    VMC(6);
    BAR; mmq(0, 2, AF0, BF1); BAR;
  }

  // ---- peeled final iteration: only Bh1(O) staged ----
  {
    const int O = 2 * NI - 1;
    rdA(0, 0, AF0); rdB(0, 0, BF0);
    STG_B(1, 1, O);
    BAR; mmq(0, 0, AF0, BF0); BAR;
    rdA(0, 4, AF1);
    BAR; mmq(4, 0, AF1, BF0); BAR;
    rdB(0, 2, BF1);
    BAR; mmq(4, 2, AF1, BF1); BAR;
    VMC(0);
    BAR; mmq(0, 2, AF0, BF1); BAR;
    rdA(65536, 0, AF0); rdB(65536, 0, BF0);
    BAR; mmq(0, 0, AF0, BF0); BAR;
    rdA(65536, 4, AF1);
    BAR; mmq(4, 0, AF1, BF0); BAR;
    rdB(65536, 2, BF1);
    BAR; mmq(4, 2, AF1, BF1); BAR;
    mmq(0, 2, AF0, BF1);
  }

  // ---- epilogue ----
  #pragma unroll
  for (int mi = 0; mi < 8; ++mi) {
    #pragma unroll
    for (int ni = 0; ni < 4; ++ni) {
      #pragma unroll
      for (int i = 0; i < 4; ++i) {
        const int r = m0 + wr * 128 + mi * 16 + quad * 4 + i;
        const int c = n0 + wc * 64 + ni * 16 + l15;
        const size_t idx = (size_t)r * N + c;
        float v = acc[mi][ni][i] + bias[c];
        if (MODE == 0) {
          ((h16*)out)[idx] = (h16)v;
        } else if (MODE == 1) {
          v += ((const float*)res)[idx];
          ((h16*)out)[idx] = (h16)v;
        } else if (MODE == 2) {
          const float e = __expf(v * (-1.5957691216f - 0.0713548163f * v * v));
          v = v / (1.0f + e);
          ((h16*)out)[idx] = (h16)v;
        } else {
          v += (float)((const h16*)res)[idx];
          ((float*)out)[idx] = v;
        }
      }
    }
  }
#undef STG_A
#undef STG_B
}

// ========== gemm201n: 8-phase, 256x128 tile, 8 waves 4Mx2N (64x64), BK=64 ==========
// r14 cadence with 6-load tiles (A halves 2 gl2lds, B halves 1) -> vmcnt(5).
#define GEMM201N_LDS 98304

template <int MODE>
__global__ __launch_bounds__(512, 2) void gemm201n(
    const h16* __restrict__ A, const h16* __restrict__ BT,
    const float* __restrict__ bias, const void* __restrict__ res,
    void* __restrict__ out, int M, int N, int K)
{
  extern __shared__ __align__(16) char smem[];
  const int tid = threadIdx.x;
  const int lane = tid & 63, w = tid >> 6;
  const int l15 = lane & 15, quad = lane >> 4;
  const int wr = w >> 1, wc = w & 1;               // 4M x 2N waves, 64x64 each
  const int m0 = blockIdx.y * 256, n0 = blockIdx.x * 128;
  const int NI = K >> 7;                           // iterations (2 K-tiles each)

  const int sr = tid >> 3;
  const int sk = ((tid & 7) ^ (sr & 7)) * 8;
  const h16* gAs = A + (size_t)(m0 + sr) * K + sk;
  const h16* gBs = BT + (size_t)(n0 + sr) * K + sk;
  const int dst0 = tid * 16;

  const int x7 = l15 & 7;
  const int sw0 = (quad ^ x7) << 4;
  const int sw1 = ((4 + quad) ^ x7) << 4;
  const int aBase = wr * 8192;                     // A region 32KB, 64 rows/wave
  const int bBase = 32768 + wc * 8192;             // B region 16KB, 64 rows/wave

  f32x4 zero = {0.f, 0.f, 0.f, 0.f};
  f32x4 acc[4][4];
  #pragma unroll
  for (int a = 0; a < 4; ++a)
    #pragma unroll
    for (int b = 0; b < 4; ++b) acc[a][b] = zero;

  f16x8 AF0[2][2], AF1[2][2], BF0[2][2], BF1[2][2];

  auto rdA = [&](int bufo, int mi0, f16x8 (&AF)[2][2]) {
    #pragma unroll
    for (int mi = 0; mi < 2; ++mi) {
      const char* p = smem + bufo + aBase + ((mi0 + mi) * 16 + l15) * 128;
      AF[mi][0] = *(const f16x8*)(p + sw0);
      AF[mi][1] = *(const f16x8*)(p + sw1);
    }
  };
  auto rdB = [&](int bufo, int ni0, f16x8 (&BF)[2][2]) {
    #pragma unroll
    for (int ni = 0; ni < 2; ++ni) {
      const char* p = smem + bufo + bBase + ((ni0 + ni) * 16 + l15) * 128;
      BF[ni][0] = *(const f16x8*)(p + sw0);
      BF[ni][1] = *(const f16x8*)(p + sw1);
    }
  };
  auto mmq = [&](int mi0, int ni0, f16x8 (&AF)[2][2], f16x8 (&BF)[2][2]) {
    __builtin_amdgcn_s_setprio(1);
    #pragma unroll
    for (int mi = 0; mi < 2; ++mi)
      #pragma unroll
      for (int ni = 0; ni < 2; ++ni) {
        acc[mi0 + mi][ni0 + ni] = __builtin_amdgcn_mfma_f32_16x16x32_f16(
            AF[mi][0], BF[ni][0], acc[mi0 + mi][ni0 + ni], 0, 0, 0);
        acc[mi0 + mi][ni0 + ni] = __builtin_amdgcn_mfma_f32_16x16x32_f16(
            AF[mi][1], BF[ni][1], acc[mi0 + mi][ni0 + ni], 0, 0, 0);
      }
    __builtin_amdgcn_s_setprio(0);
  };

  // buffer stride 48KB; A halves = 128 rows (16KB, 2 loads); B halves = 64 rows (8KB, 1).
#define STG_A(b, h, T) { \
    char* d_ = smem + (b) * 49152 + (h) * 16384 + dst0; \
    const h16* g_ = gAs + (size_t)((h) * 128) * K + (size_t)(T) * 64; \
    gl2lds16(g_, d_); gl2lds16(g_ + (size_t)64 * K, d_ + 8192); }
#define STG_B(b, h, T) { \
    char* d_ = smem + (b) * 49152 + 32768 + (h) * 8192 + dst0; \
    const h16* g_ = gBs + (size_t)((h) * 64) * K + (size_t)(T) * 64; \
    gl2lds16(g_, d_); }

  // ---- prologue: tile0 (6 loads) + tile1 {Ah0, Ah1, Bh0} (5 loads) ----
  STG_A(0, 0, 0); STG_A(0, 1, 0); STG_B(0, 0, 0); STG_B(0, 1, 0);
  STG_A(1, 0, 1); STG_A(1, 1, 1); STG_B(1, 0, 1);
  VMC(5);                                          // tile0 resident; 5 in flight
  BAR;

  for (int i = 0; i < NI - 1; ++i) {
    const int E = 2 * i, O = E + 1;
    // P1
    rdA(0, 0, AF0); rdB(0, 0, BF0);
    STG_B(1, 1, O);
    BAR; mmq(0, 0, AF0, BF0); BAR;
    // P2 (buf0 A last read)
    rdA(0, 2, AF1);
    BAR; mmq(2, 0, AF1, BF0); BAR;
    // P3 (buf0 B last read); stage Ah0(E+2)
    rdB(0, 2, BF1);
    STG_A(0, 0, E + 2);
    BAR; mmq(2, 2, AF1, BF1); BAR;
    // P4: stage Ah1+Bh0(E+2); wait drains tile O's 6 loads
    STG_A(0, 1, E + 2); STG_B(0, 0, E + 2);
    VMC(5);
    BAR; mmq(0, 2, AF0, BF1); BAR;
    // P5
    rdA(49152, 0, AF0); rdB(49152, 0, BF0);
    STG_B(0, 1, E + 2);
    BAR; mmq(0, 0, AF0, BF0); BAR;
    // P6 (buf1 A last read)
    rdA(49152, 2, AF1);
    BAR; mmq(2, 0, AF1, BF0); BAR;
    // P7 (buf1 B last read); stage Ah0(O+2)
    rdB(49152, 2, BF1);
    STG_A(1, 0, O + 2);
    BAR; mmq(2, 2, AF1, BF1); BAR;
    // P8: stage Ah1+Bh0(O+2); wait drains tile E+2's 6 loads
    STG_A(1, 1, O + 2); STG_B(1, 0, O + 2);
    VMC(5);
    BAR; mmq(0, 2, AF0, BF1); BAR;
  }

  // ---- peeled final iteration: only Bh1(O) staged ----
  {
    const int O = 2 * NI - 1;
    rdA(0, 0, AF0); rdB(0, 0, BF0);
    STG_B(1, 1, O);
    BAR; mmq(0, 0, AF0, BF0); BAR;
    rdA(0, 2, AF1);
    BAR; mmq(2, 0, AF1, BF0); BAR;
    rdB(0, 2, BF1);
    BAR; mmq(2, 2, AF1, BF1); BAR;
    VMC(0);
    BAR; mmq(0, 2, AF0, BF1); BAR;
    rdA(49152, 0, AF0); rdB(49152, 0, BF0);
    BAR; mmq(0, 0, AF0, BF0); BAR;
    rdA(49152, 2, AF1);
    BAR; mmq(2, 0, AF1, BF0); BAR;
    rdB(49152, 2, BF1);
    BAR; mmq(2, 2, AF1, BF1); BAR;
    mmq(0, 2, AF0, BF1);
  }

  // ---- epilogue ----
  #pragma unroll
  for (int mi = 0; mi < 4; ++mi) {
    #pragma unroll
    for (int ni = 0; ni < 4; ++ni) {
      #pragma unroll
      for (int i = 0; i < 4; ++i) {
        const int r = m0 + wr * 64 + mi * 16 + quad * 4 + i;
        const int c = n0 + wc * 64 + ni * 16 + l15;
        const size_t idx = (size_t)r * N + c;
        float v = acc[mi][ni][i] + bias[c];
        if (MODE == 0) {
          ((h16*)out)[idx] = (h16)v;
        } else if (MODE == 1) {
          v += ((const float*)res)[idx];
          ((h16*)out)[idx] = (h16)v;
        } else if (MODE == 2) {
          const float e = __expf(v * (-1.5957691216f - 0.0713548163f * v * v));
          v = v / (1.0f + e);
          ((h16*)out)[idx] = (h16)v;
        } else {
          v += (float)((const h16*)res)[idx];
          ((float*)out)[idx] = v;
        }
      }
    }
  }
#undef STG_A
#undef STG_B
#undef BAR
#undef VMC
}

// ---------------- Flash attention (no-max softmax): qkv f16 -> ctx f16 --------------
__global__ __launch_bounds__(256, 2) void attn_kernel(
    const h16* __restrict__ qkv, h16* __restrict__ ctx)
{
  const int qb = blockIdx.x;
  const int bh = blockIdx.y;
  const int b = bh >> 4, h = bh & 15;
  const int tid = threadIdx.x;
  const int w = tid >> 6, lane = tid & 63;
  const int l15 = lane & 15, quad = lane >> 4;

  __shared__ __align__(16) h16 Ks[64 * 80];
  __shared__ __align__(16) h16 Vt[64 * 80];
  __shared__ __align__(16) h16 Ps[256 * 80];

  const size_t qrow0 = (size_t)(b * 1024 + qb * 256);
  for (int c = tid; c < 2048; c += 256) {
    const int row = c >> 3, kc = (c & 7) * 8;
    uint4 raw = *(const uint4*)(qkv + (qrow0 + row) * 3072 + h * 64 + kc);
    union { uint4 v; h16 e[8]; } in4, out4;
    in4.v = raw;
    #pragma unroll
    for (int i = 0; i < 8; ++i) out4.e[i] = in4.e[i] * (h16)0.125f;
    *(uint4*)&Ps[row * 80 + kc] = out4.v;
  }
  __syncthreads();
  f16x8 aq[4][2];
  #pragma unroll
  for (int r = 0; r < 4; ++r)
    #pragma unroll
    for (int s = 0; s < 2; ++s)
      aq[r][s] = *(const f16x8*)&Ps[(w * 64 + r * 16 + l15) * 80 + s * 32 + quad * 8];

  f32x4 zero = {0.f, 0.f, 0.f, 0.f};
  f32x4 o_acc[4][4];
  float l_p[4][4];
  #pragma unroll
  for (int r = 0; r < 4; ++r)
    #pragma unroll
    for (int i = 0; i < 4; ++i) { o_acc[r][i] = zero; l_p[r][i] = 0.f; }

  h16* Pw = &Ps[w * 64 * 80];

  for (int jt = 0; jt < 16; ++jt) {
    __syncthreads();
    const size_t kv0 = (size_t)(b * 1024 + jt * 64);
    for (int c = tid; c < 512; c += 256) {
      const int row = c >> 3, kc = (c & 7) * 8;
      *(uint4*)&Ks[row * 80 + kc] =
          *(const uint4*)(qkv + (kv0 + row) * 3072 + 1024 + h * 64 + kc);
    }
    #pragma unroll
    for (int cc = 0; cc < 2; ++cc) {
      const int d0 = (w + cc * 4) * 8;
      uint4 raw = *(const uint4*)(qkv + (kv0 + lane) * 3072 + 2048 + h * 64 + d0);
      union { uint4 v; h16 e[8]; } in4;
      in4.v = raw;
      #pragma unroll
      for (int i = 0; i < 8; ++i) Vt[(d0 + i) * 80 + lane] = in4.e[i];
    }
    __syncthreads();

    f16x8 kf[4][2];
    #pragma unroll
    for (int ni = 0; ni < 4; ++ni)
      #pragma unroll
      for (int s = 0; s < 2; ++s)
        kf[ni][s] = *(const f16x8*)&Ks[(ni * 16 + l15) * 80 + s * 32 + quad * 8];
    #pragma unroll
    for (int r = 0; r < 4; ++r) {
      f32x4 s_acc[4];
      #pragma unroll
      for (int i = 0; i < 4; ++i) s_acc[i] = zero;
      #pragma unroll
      for (int ni = 0; ni < 4; ++ni)
        #pragma unroll
        for (int s = 0; s < 2; ++s)
          s_acc[ni] = __builtin_amdgcn_mfma_f32_16x16x32_f16(aq[r][s], kf[ni][s], s_acc[ni], 0, 0, 0);
      #pragma unroll
      for (int ni = 0; ni < 4; ++ni)
        #pragma unroll
        for (int i = 0; i < 4; ++i) {
          float p = __expf(s_acc[ni][i]);
          l_p[r][i] += p;
          Pw[(r * 16 + quad * 4 + i) * 80 + ni * 16 + l15] = (h16)p;
        }
    }

    f16x8 vf[4][2];
    #pragma unroll
    for (int ni = 0; ni < 4; ++ni)
      #pragma unroll
      for (int s = 0; s < 2; ++s)
        vf[ni][s] = *(const f16x8*)&Vt[(ni * 16 + l15) * 80 + s * 32 + quad * 8];
    #pragma unroll
    for (int r = 0; r < 4; ++r) {
      f16x8 ap0 = *(const f16x8*)&Pw[(r * 16 + l15) * 80 + quad * 8];
      f16x8 ap1 = *(const f16x8*)&Pw[(r * 16 + l15) * 80 + 32 + quad * 8];
      #pragma unroll
      for (int ni = 0; ni < 4; ++ni) {
        o_acc[r][ni] = __builtin_amdgcn_mfma_f32_16x16x32_f16(ap0, vf[ni][0], o_acc[r][ni], 0, 0, 0);
        o_acc[r][ni] = __builtin_amdgcn_mfma_f32_16x16x32_f16(ap1, vf[ni][1], o_acc[r][ni], 0, 0, 0);
      }
    }
  }

  #pragma unroll
  for (int r = 0; r < 4; ++r)
    #pragma unroll
    for (int i = 0; i < 4; ++i) {
      float lt = l_p[r][i];
      #pragma unroll
      for (int off = 1; off < 16; off <<= 1) lt += __shfl_xor(lt, off);
      const float rinv = 1.0f / lt;
      const size_t row = qrow0 + w * 64 + r * 16 + quad * 4 + i;
      #pragma unroll
      for (int ni = 0; ni < 4; ++ni)
        ctx[row * 1024 + h * 64 + ni * 16 + l15] = (h16)(o_acc[r][ni][i] * rinv);
    }
}

// ---------------- launcher ----------------
extern "C" void kernel_launch(void* const* d_in, const int* in_sizes, int n_in,
                              void* d_out, int out_size, void* d_ws, size_t ws_size,
                              hipStream_t stream) {
  const float* x   = (const float*)d_in[0];
  const float* Wq  = (const float*)d_in[1];
  const float* bq  = (const float*)d_in[2];
  const float* Wk  = (const float*)d_in[3];
  const float* bk  = (const float*)d_in[4];
  const float* Wv  = (const float*)d_in[5];
  const float* bv  = (const float*)d_in[6];
  const float* Wo  = (const float*)d_in[7];
  const float* bo  = (const float*)d_in[8];
  const float* g1  = (const float*)d_in[9];
  const float* be1 = (const float*)d_in[10];
  const float* g2  = (const float*)d_in[11];
  const float* be2 = (const float*)d_in[12];
  const float* W1  = (const float*)d_in[13];
  const float* c1  = (const float*)d_in[14];
  const float* W2  = (const float*)d_in[15];
  const float* c2  = (const float*)d_in[16];

  char* ws = (char*)d_ws;
  h16*   WqkvT = (h16*)(ws + 0);
  h16*   WoT   = (h16*)(ws + 6291456);
  h16*   W1T   = (h16*)(ws + 8388608);
  h16*   W2T   = (h16*)(ws + 16777216);
  float* bqkv  = (float*)(ws + 25165824);
  h16*   bufA  = (h16*)(ws + 25178112);    // xn1 / ctx / xn2
  h16*   qkv   = (h16*)(ws + 41955328);
  h16*   x1    = (h16*)(ws + 41955328);    // aliases dead qkv
  h16*   hbuf  = (h16*)(ws + 58732544);

  static bool attr_done = false;
  if (!attr_done) {
    hipFuncSetAttribute((const void*)gemm201<2>, hipFuncAttributeMaxDynamicSharedMemorySize, GEMM201_LDS);
    hipFuncSetAttribute((const void*)gemm201n<0>, hipFuncAttributeMaxDynamicSharedMemorySize, GEMM201N_LDS);
    hipFuncSetAttribute((const void*)gemm201n<1>, hipFuncAttributeMaxDynamicSharedMemorySize, GEMM201N_LDS);
    hipFuncSetAttribute((const void*)gemm201n<3>, hipFuncAttributeMaxDynamicSharedMemorySize, GEMM201N_LDS);
    attr_done = true;
  }

  repack_kernel<<<dim3(3073), dim3(256), 0, stream>>>(Wq, Wk, Wv, Wo, W1, W2, bq, bk, bv,
                                                      WqkvT, WoT, W1T, W2T, bqkv);
  ln_kernel<0><<<dim3(8192), dim3(256), 0, stream>>>(x, g1, be1, bufA);        // xn1
  gemm201n<0><<<dim3(24, 32), dim3(512), GEMM201N_LDS, stream>>>(bufA, WqkvT, bqkv, nullptr, qkv,
                                                                 8192, 3072, 1024);
  attn_kernel<<<dim3(4, 128), dim3(256), 0, stream>>>(qkv, bufA);              // ctx
  gemm201n<1><<<dim3(8, 32), dim3(512), GEMM201N_LDS, stream>>>(bufA, WoT, bo, x, x1,
                                                                8192, 1024, 1024);
  ln_kernel<1><<<dim3(8192), dim3(256), 0, stream>>>(x1, g2, be2, bufA);       // xn2
  gemm201<2><<<dim3(16, 32), dim3(512), GEMM201_LDS, stream>>>(bufA, W1T, c1, nullptr, hbuf,
                                                               8192, 4096, 1024);
  gemm201n<3><<<dim3(8, 32), dim3(512), GEMM201N_LDS, stream>>>(hbuf, W2T, c2, x1, d_out,
                                                                8192, 1024, 4096);
}